// Round 11
// baseline (823.918 us; speedup 1.0000x reference)
//
#include <hip/hip_runtime.h>
#include <stdint.h>

#define HH 8
#define DDIM 512
#define KHEAD 64
#define FFD 64
#define LLEN 512
#define BBATCH 32
#define NTOK 16384  // L*B

typedef unsigned short u16;
typedef __attribute__((ext_vector_type(8))) __bf16 bf16x8;
typedef __attribute__((ext_vector_type(4))) float f32x4;

__device__ __forceinline__ float bf2f(u16 u) {
    union { uint32_t i; float f; } v; v.i = ((uint32_t)u) << 16; return v.f;
}
__device__ __forceinline__ u16 f2bf(float f) {
    union { uint32_t i; float f; } v; v.f = f;
    return (u16)((v.i + 0x7FFFu + ((v.i >> 16) & 1u)) >> 16);
}

__device__ __forceinline__ void gload16(const void* g, void* l) {
    __builtin_amdgcn_global_load_lds(
        (const __attribute__((address_space(1))) void*)g,
        (__attribute__((address_space(3))) void*)l, 16, 0, 0);
}

// fp32 -> bf16 (RNE), 4 elems/thread
__global__ __launch_bounds__(256) void f2bf4(const float* __restrict__ in,
                                             u16* __restrict__ out, int n4) {
    int i = blockIdx.x * 256 + threadIdx.x;
    if (i >= n4) return;
    float4 v = ((const float4*)in)[i];
    ushort4 o; o.x = f2bf(v.x); o.y = f2bf(v.y); o.z = f2bf(v.z); o.w = f2bf(v.w);
    ((ushort4*)out)[i] = o;
}

enum { M_PLAIN = 0, M_WQK = 1, M_SUBAUX = 2, M_RELU = 3, M_ADDAUX = 4, M_SCALECOL = 5 };

// MFMA batched GEMM (round-7 proven structure).
template<int BM, int BN, int MODE, int ZMAP, int SWAPXY>
__global__ __launch_bounds__(256) void mgemm(
    const u16* __restrict__ A, const u16* __restrict__ B, u16* __restrict__ C,
    int Kd, int lda, int ldb, int ldc,
    long Ash, long Asb, long Bsh, long Bsb, long Csh, long Csb, int nB2,
    const float* __restrict__ bias, int biasN,
    const void* __restrict__ auxp, long auxsh, long auxsb, int auxld)
{
    constexpr int WC = (BN == 128) ? 2 : 1;
    constexpr int WR = 4 / WC;
    constexpr int WTM = BM / WR;
    constexpr int WTN = BN / WC;
    constexpr int MF = WTM / 16;
    constexpr int NF = WTN / 16;
    constexpr int NCA = (BM * 64) / 4096;
    constexpr int NCB = (BN * 64) / 4096;
    __shared__ u16 As[2][BM * 32];
    __shared__ u16 Bs[2][BN * 32];

    const int z = blockIdx.z;
    int h2, b2;
    if (ZMAP == 0)      { h2 = z / nB2;      b2 = z % nB2; }
    else if (ZMAP == 1) { h2 = z & 7;        b2 = z >> 3; }
    else                { h2 = (z >> 3) & 7; b2 = ((z >> 6) << 3) | (z & 7); }
    const u16* Ab = A + h2 * Ash + b2 * Asb;
    const u16* Bb = B + h2 * Bsh + b2 * Bsb;
    const int bx = SWAPXY ? blockIdx.y : blockIdx.x;
    const int by = SWAPXY ? blockIdx.x : blockIdx.y;
    const int m0 = bx * BM, n0 = by * BN;
    const int t = threadIdx.x;
    const int lane = t & 63;
    const int w = t >> 6;
    const int wr = w / WC, wc = w % WC;
    const int tb = t * 16;
    const int wb = (t & 192) * 16;

    f32x4 acc[MF][NF];
    #pragma unroll
    for (int m = 0; m < MF; ++m)
        #pragma unroll
        for (int n = 0; n < NF; ++n)
            #pragma unroll
            for (int i = 0; i < 4; ++i) acc[m][n][i] = 0.f;

    const int ko = (lane >> 4) * 16;

    auto stage = [&](int buf, int k0) {
        #pragma unroll
        for (int c = 0; c < NCA; ++c) {
            const int byte = c * 4096 + tb;
            const int row = byte >> 6;
            gload16((const char*)(Ab + (long)(m0 + row) * lda + k0) + (byte & 63),
                    (char*)As[buf] + c * 4096 + wb);
        }
        #pragma unroll
        for (int c = 0; c < NCB; ++c) {
            const int byte = c * 4096 + tb;
            const int row = byte >> 6;
            gload16((const char*)(Bb + (long)(n0 + row) * ldb + k0) + (byte & 63),
                    (char*)Bs[buf] + c * 4096 + wb);
        }
    };

    stage(0, 0);
    __syncthreads();
    int cur = 0;
    const int nsteps = Kd >> 5;
    for (int s = 0; s < nsteps; ++s) {
        if (s + 1 < nsteps) stage(cur ^ 1, (s + 1) << 5);
        bf16x8 af[MF], bfr[NF];
        #pragma unroll
        for (int m = 0; m < MF; ++m)
            af[m] = *(const bf16x8*)((const char*)As[cur] + (wr * WTM + m * 16 + (lane & 15)) * 64 + ko);
        #pragma unroll
        for (int n = 0; n < NF; ++n)
            bfr[n] = *(const bf16x8*)((const char*)Bs[cur] + (wc * WTN + n * 16 + (lane & 15)) * 64 + ko);
        #pragma unroll
        for (int m = 0; m < MF; ++m)
            #pragma unroll
            for (int n = 0; n < NF; ++n)
                acc[m][n] = __builtin_amdgcn_mfma_f32_16x16x32_bf16(af[m], bfr[n], acc[m][n], 0, 0, 0);
        __syncthreads();
        cur ^= 1;
    }

    const int lr = (lane >> 4) * 4;
    const int lc = lane & 15;

    if constexpr (MODE == M_WQK) {
        const int h = (n0 + wc * WTN) >> 6;
        #pragma unroll
        for (int m = 0; m < MF; ++m) {
            #pragma unroll
            for (int i = 0; i < 4; ++i) {
                float s = 0.f;
                #pragma unroll
                for (int n = 0; n < NF; ++n) { const float v = acc[m][n][i]; s += v * v; }
                s += __shfl_xor(s, 1); s += __shfl_xor(s, 2);
                s += __shfl_xor(s, 4); s += __shfl_xor(s, 8);
                const float inv = 1.0f / fmaxf(sqrtf(s), 1e-12f);
                const int r = m0 + wr * WTM + m * 16 + lr + i;  // token = l*B + b
                const int l = r >> 5, bq = r & 31;
                const int sw = (l & 7) << 3;
                u16* rowp = C + (((long)(h * BBATCH + bq) * LLEN + l) * KHEAD);
                #pragma unroll
                for (int n = 0; n < NF; ++n)
                    rowp[(lc + n * 16) ^ sw] = f2bf(acc[m][n][i] * inv);
            }
        }
    } else {
        const long cof = h2 * Csh + b2 * Csb;
        #pragma unroll
        for (int m = 0; m < MF; ++m) {
            #pragma unroll
            for (int i = 0; i < 4; ++i) {
                const int r = m0 + wr * WTM + m * 16 + lr + i;
                #pragma unroll
                for (int n = 0; n < NF; ++n) {
                    const int c = n0 + wc * WTN + n * 16 + lc;
                    float v = acc[m][n][i];
                    if (MODE == M_SUBAUX) {
                        const u16* q = (const u16*)auxp;
                        v = bf2f(q[auxsh * h2 + auxsb * b2 + (long)r * auxld + c]) - v;
                    } else if (MODE == M_RELU) {
                        if (bias) v += bias[h2 * biasN + c];
                        v = fmaxf(v, 0.0f);
                    } else if (MODE == M_ADDAUX) {
                        v += bias[h2 * biasN + c];
                        const u16* ax = (const u16*)auxp;
                        v += bf2f(ax[auxsh * h2 + auxsb * b2 + (long)r * auxld + c]);
                    } else if (MODE == M_SCALECOL) {
                        const float* cs = (const float*)auxp + auxsh * h2 + auxsb * b2;
                        v *= 1.0f / (1e-9f + cs[c]);
                    }
                    C[cof + (long)r * ldc + c] = f2bf(v);
                }
            }
        }
    }
}

// XCD-aware decode: 8 qt-blocks of one (h,b) -> same wgid%8 (same XCD),
// adjacent dispatch slots -> wk/wvT/qbf panels L2/L3-reused.
__device__ __forceinline__ void xcd_decode(int wgid, int& qt, int& b, int& h) {
    const int r = wgid & 7;
    const int inner = wgid >> 3;
    qt = inner & 7;
    h = (inner >> 3) & 7;
    b = ((inner >> 6) << 3) | r;
}

// Pass A: softmax column sums ONLY (no P materialization).
__global__ __launch_bounds__(256) void attn_sums(
    const u16* __restrict__ wq, const u16* __restrict__ wk,
    float* __restrict__ colsum)
{
    __shared__ u16 qs[64 * 64];
    __shared__ u16 ks[512 * 64];
    __shared__ float smax[4][64];
    __shared__ float ssum[4][64];

    int qt, b, h;
    xcd_decode(blockIdx.x, qt, b, h);
    const long hb = h * BBATCH + b;
    const int t = threadIdx.x;
    const int lane = t & 63, w = t >> 6;
    const int wb = (t & 192) * 16;

    const char* qg = (const char*)(wq + (hb * LLEN + qt * 64) * KHEAD);
    const char* kg = (const char*)(wk + hb * LLEN * KHEAD);
    #pragma unroll
    for (int c = 0; c < 2; ++c)
        gload16(qg + c * 4096 + t * 16, (char*)qs + c * 4096 + wb);
    #pragma unroll
    for (int c = 0; c < 16; ++c)
        gload16(kg + c * 4096 + t * 16, (char*)ks + c * 4096 + wb);
    __syncthreads();

    const int l15 = lane & 15;
    const int g = lane >> 4;
    const int swz = (lane & 7) << 4;

    f32x4 acc[4][8];
    #pragma unroll
    for (int m = 0; m < 4; ++m)
        #pragma unroll
        for (int n = 0; n < 8; ++n)
            #pragma unroll
            for (int i = 0; i < 4; ++i) acc[m][n][i] = 0.f;

    #pragma unroll
    for (int kk = 0; kk < 2; ++kk) {
        bf16x8 af[4];
        #pragma unroll
        for (int m = 0; m < 4; ++m) {
            const int row = m * 16 + l15;
            af[m] = *(const bf16x8*)((const char*)qs + row * 128 + ((g * 16 + kk * 64) ^ swz));
        }
        #pragma unroll
        for (int n = 0; n < 8; ++n) {
            const int row = (w * 8 + n) * 16 + l15;
            const bf16x8 bfr = *(const bf16x8*)((const char*)ks + row * 128 + ((g * 16 + kk * 64) ^ swz));
            #pragma unroll
            for (int m = 0; m < 4; ++m)
                acc[m][n] = __builtin_amdgcn_mfma_f32_16x16x32_bf16(af[m], bfr, acc[m][n], 0, 0, 0);
        }
    }

    float rmax[4][4];
    #pragma unroll
    for (int m = 0; m < 4; ++m)
        #pragma unroll
        for (int i = 0; i < 4; ++i) {
            float mx = acc[m][0][i];
            #pragma unroll
            for (int n = 1; n < 8; ++n) mx = fmaxf(mx, acc[m][n][i]);
            mx = fmaxf(mx, __shfl_xor(mx, 1));
            mx = fmaxf(mx, __shfl_xor(mx, 2));
            mx = fmaxf(mx, __shfl_xor(mx, 4));
            mx = fmaxf(mx, __shfl_xor(mx, 8));
            if (l15 == 0) smax[w][m * 16 + g * 4 + i] = mx;
        }
    __syncthreads();
    #pragma unroll
    for (int m = 0; m < 4; ++m)
        #pragma unroll
        for (int i = 0; i < 4; ++i) {
            const int r = m * 16 + g * 4 + i;
            rmax[m][i] = fmaxf(fmaxf(smax[0][r], smax[1][r]),
                               fmaxf(smax[2][r], smax[3][r]));
        }
    float rinv[4][4];
    #pragma unroll
    for (int m = 0; m < 4; ++m)
        #pragma unroll
        for (int i = 0; i < 4; ++i) {
            float s = 0.f;
            #pragma unroll
            for (int n = 0; n < 8; ++n) {
                acc[m][n][i] = __expf(acc[m][n][i] - rmax[m][i]);
                s += acc[m][n][i];
            }
            s += __shfl_xor(s, 1); s += __shfl_xor(s, 2);
            s += __shfl_xor(s, 4); s += __shfl_xor(s, 8);
            if (l15 == 0) ssum[w][m * 16 + g * 4 + i] = s;
        }
    __syncthreads();
    #pragma unroll
    for (int m = 0; m < 4; ++m)
        #pragma unroll
        for (int i = 0; i < 4; ++i) {
            const int r = m * 16 + g * 4 + i;
            rinv[m][i] = 1.0f / (ssum[0][r] + ssum[1][r] + ssum[2][r] + ssum[3][r]);
        }

    float cs[8];
    #pragma unroll
    for (int n = 0; n < 8; ++n) cs[n] = 0.f;
    #pragma unroll
    for (int m = 0; m < 4; ++m)
        #pragma unroll
        for (int i = 0; i < 4; ++i) {
            const float iv = rinv[m][i];
            #pragma unroll
            for (int n = 0; n < 8; ++n) cs[n] += acc[m][n][i] * iv;
        }
    #pragma unroll
    for (int n = 0; n < 8; ++n) {
        cs[n] += __shfl_xor(cs[n], 16);
        cs[n] += __shfl_xor(cs[n], 32);
    }
    if (lane < 16) {
        float* cb = colsum + hb * 512 + w * 128 + lane;
        #pragma unroll
        for (int n = 0; n < 8; ++n) atomicAdd(&cb[n * 16], cs[n]);
    }
}

// Pass B: recompute softmax(QK^T), P in LDS only, PV with V streamed
// GLOBAL->REG (L2-resident panel; no LDS staging, no PV-loop barriers).
// LDS 76 KB -> 2 blocks/CU. 8 waves, 512 threads. XCD-aware block decode.
__global__ __launch_bounds__(512) void attn_pv(
    const u16* __restrict__ wq, const u16* __restrict__ wk,
    const u16* __restrict__ wvT, const u16* __restrict__ qbf,
    u16* __restrict__ qmo)
{
    __shared__ u16 qs[64 * 64];        // 8 KB
    __shared__ u16 ksP[512 * 64];      // 64 KB: K staging -> P overlay
    __shared__ float smax[8][64];
    __shared__ float ssum[8][64];

    int qt, b, h;
    xcd_decode(blockIdx.x, qt, b, h);
    const long hb = h * BBATCH + b;
    const int t = threadIdx.x;
    const int lane = t & 63, w = t >> 6;
    const int l15 = lane & 15, g = lane >> 4;
    const int wb = (t & 448) * 16;     // wave dest base: w*1024

    // ---- stage Q (8 KB) + K (64 KB) ----
    const char* qg = (const char*)(wq + (hb * LLEN + qt * 64) * KHEAD);
    const char* kg = (const char*)(wk + hb * LLEN * KHEAD);
    gload16(qg + t * 16, (char*)qs + wb);
    #pragma unroll
    for (int c = 0; c < 8; ++c)
        gload16(kg + c * 8192 + t * 16, (char*)ksP + c * 8192 + wb);
    __syncthreads();

    const int swz = (l15 & 7) << 4;

    // ---- S = QK^T for this wave's 64 k-cols ----
    f32x4 acc[4][4];
    #pragma unroll
    for (int m = 0; m < 4; ++m)
        #pragma unroll
        for (int n = 0; n < 4; ++n)
            #pragma unroll
            for (int i = 0; i < 4; ++i) acc[m][n][i] = 0.f;

    #pragma unroll
    for (int kk = 0; kk < 2; ++kk) {
        bf16x8 af[4];
        #pragma unroll
        for (int m = 0; m < 4; ++m) {
            const int row = m * 16 + l15;
            af[m] = *(const bf16x8*)((const char*)qs + row * 128 + ((g * 16 + kk * 64) ^ swz));
        }
        #pragma unroll
        for (int n = 0; n < 4; ++n) {
            const int row = w * 64 + n * 16 + l15;
            const bf16x8 bfr = *(const bf16x8*)((const char*)ksP + row * 128 + ((g * 16 + kk * 64) ^ swz));
            #pragma unroll
            for (int m = 0; m < 4; ++m)
                acc[m][n] = __builtin_amdgcn_mfma_f32_16x16x32_bf16(af[m], bfr, acc[m][n], 0, 0, 0);
        }
    }

    // ---- softmax across 8 waves ----
    #pragma unroll
    for (int m = 0; m < 4; ++m)
        #pragma unroll
        for (int i = 0; i < 4; ++i) {
            float mx = acc[m][0][i];
            #pragma unroll
            for (int n = 1; n < 4; ++n) mx = fmaxf(mx, acc[m][n][i]);
            mx = fmaxf(mx, __shfl_xor(mx, 1));
            mx = fmaxf(mx, __shfl_xor(mx, 2));
            mx = fmaxf(mx, __shfl_xor(mx, 4));
            mx = fmaxf(mx, __shfl_xor(mx, 8));
            if (l15 == 0) smax[w][m * 16 + g * 4 + i] = mx;
        }
    __syncthreads();
    float rmax[4][4];
    #pragma unroll
    for (int m = 0; m < 4; ++m)
        #pragma unroll
        for (int i = 0; i < 4; ++i) {
            const int r = m * 16 + g * 4 + i;
            float mx = smax[0][r];
            #pragma unroll
            for (int ww = 1; ww < 8; ++ww) mx = fmaxf(mx, smax[ww][r]);
            rmax[m][i] = mx;
        }
    #pragma unroll
    for (int m = 0; m < 4; ++m)
        #pragma unroll
        for (int i = 0; i < 4; ++i) {
            float s = 0.f;
            #pragma unroll
            for (int n = 0; n < 4; ++n) {
                acc[m][n][i] = __expf(acc[m][n][i] - rmax[m][i]);
                s += acc[m][n][i];
            }
            s += __shfl_xor(s, 1); s += __shfl_xor(s, 2);
            s += __shfl_xor(s, 4); s += __shfl_xor(s, 8);
            if (l15 == 0) ssum[w][m * 16 + g * 4 + i] = s;
        }
    __syncthreads();
    float rinv[4][4];
    #pragma unroll
    for (int m = 0; m < 4; ++m)
        #pragma unroll
        for (int i = 0; i < 4; ++i) {
            const int r = m * 16 + g * 4 + i;
            float s = ssum[0][r];
            #pragma unroll
            for (int ww = 1; ww < 8; ++ww) s += ssum[ww][r];
            rinv[m][i] = 1.0f / s;
        }

    // ---- preload first V column-chunk into registers (L2-resident) ----
    const u16* wvb = wvT + hb * (long)DDIM * LLEN;   // [512 e][512 l]
    bf16x8 vbr[4];
    #pragma unroll
    for (int n = 0; n < 4; ++n) {
        const int row = w * 64 + n * 16 + l15;
        vbr[n] = *(const bf16x8*)(wvb + (long)row * LLEN + g * 8);
    }

    // ---- P -> LDS (overlay ks; granule-XOR swizzle G ^= q&7) ----
    #pragma unroll
    for (int m = 0; m < 4; ++m)
        #pragma unroll
        for (int i = 0; i < 4; ++i) {
            const int q = m * 16 + g * 4 + i;
            const float iv = rinv[m][i];
            #pragma unroll
            for (int n = 0; n < 4; ++n) {
                const int k = w * 64 + n * 16 + l15;
                const int Gs = (k >> 3) ^ (q & 7);
                *(u16*)((char*)ksP + q * 1024 + Gs * 16 + (k & 7) * 2) =
                    f2bf(acc[m][n][i] * iv);
            }
        }
    __syncthreads();   // P visible; last barrier in the kernel

    // ---- PV: O = P @ wvT^T, V reg-double-buffered, NO barriers ----
    f32x4 o[4][4];
    #pragma unroll
    for (int m = 0; m < 4; ++m)
        #pragma unroll
        for (int n = 0; n < 4; ++n)
            #pragma unroll
            for (int i = 0; i < 4; ++i) o[m][n][i] = 0.f;

    for (int s = 0; s < 16; ++s) {
        bf16x8 vnx[4];
        if (s + 1 < 16) {
            #pragma unroll
            for (int n = 0; n < 4; ++n) {
                const int row = w * 64 + n * 16 + l15;
                vnx[n] = *(const bf16x8*)(wvb + (long)row * LLEN + (s + 1) * 32 + g * 8);
            }
        }
        bf16x8 pa[4];
        #pragma unroll
        for (int m = 0; m < 4; ++m) {
            const int q = m * 16 + l15;
            pa[m] = *(const bf16x8*)((const char*)ksP + q * 1024 +
                                     (((s * 4 + g) ^ (q & 7)) << 4));
        }
        #pragma unroll
        for (int n = 0; n < 4; ++n)
            #pragma unroll
            for (int m = 0; m < 4; ++m)
                o[m][n] = __builtin_amdgcn_mfma_f32_16x16x32_bf16(pa[m], vbr[n], o[m][n], 0, 0, 0);
        #pragma unroll
        for (int n = 0; n < 4; ++n) vbr[n] = vnx[n];
    }

    // ---- epilogue: qmo = query - O ----
    #pragma unroll
    for (int m = 0; m < 4; ++m)
        #pragma unroll
        for (int i = 0; i < 4; ++i) {
            const int q = qt * 64 + m * 16 + g * 4 + i;   // sequence pos l
            const u16* qrow = qbf + ((long)q * BBATCH + b) * DDIM;
            u16* orow = qmo + (hb * LLEN + q) * DDIM;
            #pragma unroll
            for (int n = 0; n < 4; ++n) {
                const int e = w * 64 + n * 16 + l15;
                orow[e] = f2bf(bf2f(qrow[e]) - o[m][n][i]);
            }
        }
}

// Fused: preLN = o + hff @ W2^T + b2, LayerNorm, transpose-scatter fp32.
__global__ __launch_bounds__(256) void ffn2_ln(
    const u16* __restrict__ hff, const u16* __restrict__ W2bf,
    const float* __restrict__ b2, const u16* __restrict__ o,
    const float* __restrict__ lng, const float* __restrict__ lnb,
    float* __restrict__ out)
{
    __shared__ u16 W2s[512 * 64];
    __shared__ u16 hs[32 * 64];
    __shared__ float redS[4][32];
    __shared__ float redQ[4][32];

    const int h = blockIdx.z;
    const int m0 = blockIdx.x * 32;
    const int t = threadIdx.x;
    const int lane = t & 63, w = t >> 6;
    const int l15 = lane & 15, g = lane >> 4;
    const int wb = (t & 192) * 16;

    const char* w2g = (const char*)W2bf + (long)h * 65536;
    #pragma unroll
    for (int c = 0; c < 16; ++c) {
        const int idx = c * 4096 + t * 16;
        const int row = idx >> 7;
        const int g0 = (idx >> 4) & 7;
        gload16(w2g + row * 128 + ((g0 ^ (row & 7)) << 4),
                (char*)W2s + c * 4096 + wb);
    }
    {
        const int idx = t * 16;
        const int row = idx >> 7;
        const int g0 = (idx >> 4) & 7;
        gload16((const char*)(hff + ((long)h * NTOK + m0) * FFD) +
                    row * 128 + ((g0 ^ (row & 7)) << 4),
                (char*)hs + wb);
    }
    __syncthreads();

    f32x4 acc[2][8];
    #pragma unroll
    for (int m = 0; m < 2; ++m)
        #pragma unroll
        for (int n = 0; n < 8; ++n)
            #pragma unroll
            for (int i = 0; i < 4; ++i) acc[m][n][i] = 0.f;

    #pragma unroll
    for (int kk = 0; kk < 2; ++kk) {
        bf16x8 af[2];
        #pragma unroll
        for (int m = 0; m < 2; ++m) {
            const int row = m * 16 + l15;
            af[m] = *(const bf16x8*)((const char*)hs + row * 128 +
                                     (((kk * 4 + g) ^ (row & 7)) << 4));
        }
        #pragma unroll
        for (int n = 0; n < 8; ++n) {
            const int e = w * 128 + n * 16 + l15;
            const bf16x8 bfr = *(const bf16x8*)((const char*)W2s + e * 128 +
                                                (((kk * 4 + g) ^ (e & 7)) << 4));
            #pragma unroll
            for (int m = 0; m < 2; ++m)
                acc[m][n] = __builtin_amdgcn_mfma_f32_16x16x32_bf16(af[m], bfr, acc[m][n], 0, 0, 0);
        }
    }

    float b2v[8], gv[8], bv[8];
    #pragma unroll
    for (int n = 0; n < 8; ++n) {
        const int c = w * 128 + n * 16 + l15;
        b2v[n] = b2[h * DDIM + c];
        gv[n] = lng[h * DDIM + c];
        bv[n] = lnb[h * DDIM + c];
    }
    const u16* ob = o + ((long)h * NTOK + m0) * DDIM;
    #pragma unroll
    for (int m = 0; m < 2; ++m)
        #pragma unroll
        for (int i = 0; i < 4; ++i) {
            const int row = m * 16 + g * 4 + i;
            float s = 0.f, q = 0.f;
            #pragma unroll
            for (int n = 0; n < 8; ++n) {
                const int c = w * 128 + n * 16 + l15;
                const float v = acc[m][n][i] + b2v[n] + bf2f(ob[(long)row * DDIM + c]);
                acc[m][n][i] = v;
                s += v; q += v * v;
            }
            s += __shfl_xor(s, 1); q += __shfl_xor(q, 1);
            s += __shfl_xor(s, 2); q += __shfl_xor(q, 2);
            s += __shfl_xor(s, 4); q += __shfl_xor(q, 4);
            s += __shfl_xor(s, 8); q += __shfl_xor(q, 8);
            if (l15 == 0) { redS[w][row] = s; redQ[w][row] = q; }
        }
    __syncthreads();

    #pragma unroll
    for (int m = 0; m < 2; ++m)
        #pragma unroll
        for (int i = 0; i < 4; ++i) {
            const int row = m * 16 + g * 4 + i;
            const float s = redS[0][row] + redS[1][row] + redS[2][row] + redS[3][row];
            const float q = redQ[0][row] + redQ[1][row] + redQ[2][row] + redQ[3][row];
            const float mu = s * (1.0f / 512.0f);
            const float var = q * (1.0f / 512.0f) - mu * mu;
            const float rs = rsqrtf(var + 1e-5f);
            const int tok = m0 + row;
            const int b = tok >> 9, l = tok & 511;   // tok = b*512 + l
            float* op = out + ((long)(l * BBATCH + b)) * (HH * DDIM) + h * DDIM;
            #pragma unroll
            for (int n = 0; n < 8; ++n) {
                const int c = w * 128 + n * 16 + l15;
                op[c] = (acc[m][n][i] - mu) * rs * gv[n] + bv[n];
            }
        }
}

extern "C" void kernel_launch(void* const* d_in, const int* in_sizes, int n_in,
                              void* d_out, int out_size, void* d_ws, size_t ws_size,
                              hipStream_t stream) {
    const float* query = (const float*)d_in[0];
    const float* key   = (const float*)d_in[1];
    const float* value = (const float*)d_in[2];
    const float* WK = (const float*)d_in[3];
    const float* WQ = (const float*)d_in[4];
    const float* WV = (const float*)d_in[5];
    const float* Wt = (const float*)d_in[6];
    const float* W1 = (const float*)d_in[7];
    const float* b1 = (const float*)d_in[8];
    const float* W2 = (const float*)d_in[9];
    const float* b2 = (const float*)d_in[10];
    const float* lng = (const float*)d_in[11];
    const float* lnb = (const float*)d_in[12];

    // ---- workspace layout (bytes) ----
    char* ws = (char*)d_ws;
    u16* kbf  = (u16*)(ws);                    // 16 MB
    u16* WQbf = (u16*)(ws + 16777216);         // 0.5 MB
    u16* WKbf = (u16*)(ws + 17301504);         // 0.5 MB
    u16* Wtbf = (u16*)(ws + 33554432);         // 4 MB
    u16* W1bf = (u16*)(ws + 37748736);         // 0.5 MB
    u16* W2bf = (u16*)(ws + 38273024);         // 0.5 MB
    u16* vbf  = (u16*)(ws + 134217728);        // 16 MB
    u16* WVbf = (u16*)(ws + 150994944);        // 0.5 MB
    u16* o    = (u16*)(ws + 134217728);        // 128 MB (from K6)
    float* colsum = (float*)(ws + 268435456);  // 0.5 MB
    u16* qbf  = (u16*)(ws + 268959744);        // 16 MB, dead after attn_pv
    u16* hff  = qbf;                           // overlay, produced at K7
    u16* wq   = (u16*)(ws + 285736960);        // 16 MB
    u16* wk   = (u16*)(ws + 302514176);        // 16 MB
    u16* qmo = (u16*)d_out;                        // [H][B][L][D]
    u16* wvT = (u16*)((char*)d_out + 134217728);   // [H][B][D][L]

    if (ws_size < 319291392u) return;

    hipMemsetAsync(colsum, 0, 524288, stream);
    const dim3 blk(256);

    // fp32 -> bf16 conversions
    f2bf4<<<dim3(8192), blk, 0, stream>>>(query, qbf, 2097152);
    f2bf4<<<dim3(8192), blk, 0, stream>>>(key,   kbf, 2097152);
    f2bf4<<<dim3(8192), blk, 0, stream>>>(value, vbf, 2097152);
    f2bf4<<<dim3(256),  blk, 0, stream>>>(WQ, WQbf, 65536);
    f2bf4<<<dim3(256),  blk, 0, stream>>>(WK, WKbf, 65536);
    f2bf4<<<dim3(2048), blk, 0, stream>>>(WV, WVbf, 524288);
    f2bf4<<<dim3(2048), blk, 0, stream>>>(Wt, Wtbf, 524288);
    f2bf4<<<dim3(256),  blk, 0, stream>>>(W1, W1bf, 65536);
    f2bf4<<<dim3(256),  blk, 0, stream>>>(W2, W2bf, 65536);

    // K1: wq/wk = l2norm(query/key @ WQ/WK^T) -> [H,B,L,K] bf16 (swizzled rows)
    mgemm<128, 128, M_WQK, 0, 1><<<dim3(4, 128, 1), blk, 0, stream>>>(
        qbf, WQbf, wq, 512, 512, 512, 0,
        0, 0, 0, 0, 0, 0, 1, nullptr, 0, nullptr, 0, 0, 0);
    mgemm<128, 128, M_WQK, 0, 1><<<dim3(4, 128, 1), blk, 0, stream>>>(
        kbf, WKbf, wk, 512, 512, 512, 0,
        0, 0, 0, 0, 0, 0, 1, nullptr, 0, nullptr, 0, 0, 0);

    // Pass A: softmax column sums (no P write), XCD-aware decode
    attn_sums<<<dim3(2048), blk, 0, stream>>>(wq, wk, colsum);

    // K2: wvT[h,b,e,l] = (WV @ value^T) / (1e-9 + colsum[h,b,l])
    mgemm<128, 128, M_SCALECOL, 2, 0><<<dim3(4, 4, 256), blk, 0, stream>>>(
        WVbf, vbf, wvT, 512, 512, BBATCH * DDIM, 512,
        (long)DDIM * DDIM, 0, 0, DDIM,
        (long)BBATCH * DDIM * LLEN, (long)DDIM * LLEN, 32,
        nullptr, 0, colsum, (long)BBATCH * 512, 512, 0);

    // Pass B: recompute softmax + PV, qmo = query - P @ wvT^T  (P never in HBM)
    attn_pv<<<dim3(2048), dim3(512), 0, stream>>>(wq, wk, wvT, qbf, qmo);

    // K6: o = relu(qmo @ Wt^T)
    mgemm<128, 128, M_RELU, 0, 1><<<dim3(4, 128, 8), blk, 0, stream>>>(
        qmo, Wtbf, o, 512, 512, 512, 512,
        (long)NTOK * DDIM, 0, (long)DDIM * DDIM, 0,
        (long)NTOK * DDIM, 0, 1, nullptr, 512, nullptr, 0, 0, 0);

    // K7: hff = relu(o @ W1^T + b1)   (BN=64)
    mgemm<128, 64, M_RELU, 0, 0><<<dim3(128, 1, 8), blk, 0, stream>>>(
        o, W1bf, hff, 512, 512, 512, 64,
        (long)NTOK * DDIM, 0, (long)FFD * DDIM, 0,
        (long)NTOK * FFD, 0, 1, b1, 64, nullptr, 0, 0, 0);

    // K8 + LN + transpose fused
    ffn2_ln<<<dim3(512, 1, 8), blk, 0, stream>>>(hff, W2bf, b2, o, lng, lnb,
                                                 (float*)d_out);
}

// Round 12
// 766.209 us; speedup vs baseline: 1.0753x; 1.0753x over previous
//
#include <hip/hip_runtime.h>
#include <stdint.h>

#define HH 8
#define DDIM 512
#define KHEAD 64
#define FFD 64
#define LLEN 512
#define BBATCH 32
#define NTOK 16384  // L*B

typedef unsigned short u16;
typedef __attribute__((ext_vector_type(8))) __bf16 bf16x8;
typedef __attribute__((ext_vector_type(4))) float f32x4;

__device__ __forceinline__ float bf2f(u16 u) {
    union { uint32_t i; float f; } v; v.i = ((uint32_t)u) << 16; return v.f;
}
__device__ __forceinline__ u16 f2bf(float f) {
    union { uint32_t i; float f; } v; v.f = f;
    return (u16)((v.i + 0x7FFFu + ((v.i >> 16) & 1u)) >> 16);
}

__device__ __forceinline__ void gload16(const void* g, void* l) {
    __builtin_amdgcn_global_load_lds(
        (const __attribute__((address_space(1))) void*)g,
        (__attribute__((address_space(3))) void*)l, 16, 0, 0);
}

// ---- fused fp32->bf16 conversion: several tensors in one launch ----
struct ConvJob { const float* s; u16* d; int n4; };
struct ConvJobs { ConvJob j[6]; int nj; };

__global__ __launch_bounds__(256) void conv_multi(ConvJobs jobs) {
    for (int k = 0; k < jobs.nj; ++k) {
        const float* s = jobs.j[k].s;
        u16* d = jobs.j[k].d;
        const int n4 = jobs.j[k].n4;
        for (long i = (long)blockIdx.x * 256 + threadIdx.x; i < n4;
             i += (long)gridDim.x * 256) {
            float4 v = ((const float4*)s)[i];
            ushort4 o;
            o.x = f2bf(v.x); o.y = f2bf(v.y); o.z = f2bf(v.z); o.w = f2bf(v.w);
            ((ushort4*)d)[i] = o;
        }
    }
}

enum { M_PLAIN = 0, M_WQK = 1, M_SUBAUX = 2, M_RELU = 3, M_ADDAUX = 4, M_SCALECOL = 5 };

// MFMA batched GEMM (round-7 proven structure: row-major linear staging,
// double-buffered, one __syncthreads per K-step).
template<int BM, int BN, int MODE, int ZMAP, int SWAPXY>
__global__ __launch_bounds__(256) void mgemm(
    const u16* __restrict__ A, const u16* __restrict__ B, u16* __restrict__ C,
    int Kd, int lda, int ldb, int ldc,
    long Ash, long Asb, long Bsh, long Bsb, long Csh, long Csb, int nB2,
    const float* __restrict__ bias, int biasN,
    const void* __restrict__ auxp, long auxsh, long auxsb, int auxld)
{
    constexpr int WC = (BN == 128) ? 2 : 1;
    constexpr int WR = 4 / WC;
    constexpr int WTM = BM / WR;
    constexpr int WTN = BN / WC;
    constexpr int MF = WTM / 16;
    constexpr int NF = WTN / 16;
    constexpr int NCA = (BM * 64) / 4096;
    constexpr int NCB = (BN * 64) / 4096;
    __shared__ u16 As[2][BM * 32];
    __shared__ u16 Bs[2][BN * 32];

    const int z = blockIdx.z;
    int h2, b2;
    if (ZMAP == 0)      { h2 = z / nB2;      b2 = z % nB2; }
    else if (ZMAP == 1) { h2 = z & 7;        b2 = z >> 3; }
    else                { h2 = (z >> 3) & 7; b2 = ((z >> 6) << 3) | (z & 7); }
    const u16* Ab = A + h2 * Ash + b2 * Asb;
    const u16* Bb = B + h2 * Bsh + b2 * Bsb;
    const int bx = SWAPXY ? blockIdx.y : blockIdx.x;
    const int by = SWAPXY ? blockIdx.x : blockIdx.y;
    const int m0 = bx * BM, n0 = by * BN;
    const int t = threadIdx.x;
    const int lane = t & 63;
    const int w = t >> 6;
    const int wr = w / WC, wc = w % WC;
    const int tb = t * 16;
    const int wb = (t & 192) * 16;

    f32x4 acc[MF][NF];
    #pragma unroll
    for (int m = 0; m < MF; ++m)
        #pragma unroll
        for (int n = 0; n < NF; ++n)
            #pragma unroll
            for (int i = 0; i < 4; ++i) acc[m][n][i] = 0.f;

    const int ko = (lane >> 4) * 16;

    auto stage = [&](int buf, int k0) {
        #pragma unroll
        for (int c = 0; c < NCA; ++c) {
            const int byte = c * 4096 + tb;
            const int row = byte >> 6;
            gload16((const char*)(Ab + (long)(m0 + row) * lda + k0) + (byte & 63),
                    (char*)As[buf] + c * 4096 + wb);
        }
        #pragma unroll
        for (int c = 0; c < NCB; ++c) {
            const int byte = c * 4096 + tb;
            const int row = byte >> 6;
            gload16((const char*)(Bb + (long)(n0 + row) * ldb + k0) + (byte & 63),
                    (char*)Bs[buf] + c * 4096 + wb);
        }
    };

    stage(0, 0);
    __syncthreads();
    int cur = 0;
    const int nsteps = Kd >> 5;
    for (int s = 0; s < nsteps; ++s) {
        if (s + 1 < nsteps) stage(cur ^ 1, (s + 1) << 5);
        bf16x8 af[MF], bfr[NF];
        #pragma unroll
        for (int m = 0; m < MF; ++m)
            af[m] = *(const bf16x8*)((const char*)As[cur] + (wr * WTM + m * 16 + (lane & 15)) * 64 + ko);
        #pragma unroll
        for (int n = 0; n < NF; ++n)
            bfr[n] = *(const bf16x8*)((const char*)Bs[cur] + (wc * WTN + n * 16 + (lane & 15)) * 64 + ko);
        #pragma unroll
        for (int m = 0; m < MF; ++m)
            #pragma unroll
            for (int n = 0; n < NF; ++n)
                acc[m][n] = __builtin_amdgcn_mfma_f32_16x16x32_bf16(af[m], bfr[n], acc[m][n], 0, 0, 0);
        __syncthreads();
        cur ^= 1;
    }

    const int lr = (lane >> 4) * 4;
    const int lc = lane & 15;

    if constexpr (MODE == M_WQK) {
        const int h = (n0 + wc * WTN) >> 6;
        #pragma unroll
        for (int m = 0; m < MF; ++m) {
            #pragma unroll
            for (int i = 0; i < 4; ++i) {
                float s = 0.f;
                #pragma unroll
                for (int n = 0; n < NF; ++n) { const float v = acc[m][n][i]; s += v * v; }
                s += __shfl_xor(s, 1); s += __shfl_xor(s, 2);
                s += __shfl_xor(s, 4); s += __shfl_xor(s, 8);
                const float inv = 1.0f / fmaxf(sqrtf(s), 1e-12f);
                const int r = m0 + wr * WTM + m * 16 + lr + i;  // token = l*B + b
                const int l = r >> 5, bq = r & 31;
                const int sw = (l & 7) << 3;
                u16* rowp = C + (((long)(h * BBATCH + bq) * LLEN + l) * KHEAD);
                #pragma unroll
                for (int n = 0; n < NF; ++n)
                    rowp[(lc + n * 16) ^ sw] = f2bf(acc[m][n][i] * inv);
            }
        }
    } else {
        const long cof = h2 * Csh + b2 * Csb;
        #pragma unroll
        for (int m = 0; m < MF; ++m) {
            #pragma unroll
            for (int i = 0; i < 4; ++i) {
                const int r = m0 + wr * WTM + m * 16 + lr + i;
                #pragma unroll
                for (int n = 0; n < NF; ++n) {
                    const int c = n0 + wc * WTN + n * 16 + lc;
                    float v = acc[m][n][i];
                    if (MODE == M_SUBAUX) {
                        const u16* q = (const u16*)auxp;
                        v = bf2f(q[auxsh * h2 + auxsb * b2 + (long)r * auxld + c]) - v;
                    } else if (MODE == M_RELU) {
                        if (bias) v += bias[h2 * biasN + c];
                        v = fmaxf(v, 0.0f);
                    } else if (MODE == M_ADDAUX) {
                        v += bias[h2 * biasN + c];
                        const u16* ax = (const u16*)auxp;
                        v += bf2f(ax[auxsh * h2 + auxsb * b2 + (long)r * auxld + c]);
                    } else if (MODE == M_SCALECOL) {
                        const float* cs = (const float*)auxp + auxsh * h2 + auxsb * b2;
                        v *= 1.0f / (1e-9f + cs[c]);
                    }
                    C[cof + (long)r * ldc + c] = f2bf(v);
                }
            }
        }
    }
}

// XCD-aware decode: 8 qt-blocks of one (h,b) -> same wgid%8 (same XCD),
// adjacent dispatch slots -> wk panel L2-reused 8x.
__device__ __forceinline__ void xcd_decode(int wgid, int& qt, int& b, int& h) {
    const int r = wgid & 7;
    const int inner = wgid >> 3;
    qt = inner & 7;
    h = (inner >> 3) & 7;
    b = ((inner >> 6) << 3) | r;
}

// MFMA QK^T + softmax -> P (bf16) + column sums (fp32 atomics).
// One pass; 64 q-rows x 512 k per block. XCD-aware 1D grid (2048 blocks).
__global__ __launch_bounds__(256) void attn_mfma(
    const u16* __restrict__ wq, const u16* __restrict__ wk,
    u16* __restrict__ P, float* __restrict__ colsum)
{
    __shared__ u16 qs[64 * 64];
    __shared__ u16 ks[512 * 64];
    __shared__ float smax[4][64];
    __shared__ float ssum[4][64];

    int qt, b, h;
    xcd_decode(blockIdx.x, qt, b, h);
    const long hb = h * BBATCH + b;
    const int t = threadIdx.x;
    const int lane = t & 63, w = t >> 6;
    const int wb = (t & 192) * 16;

    const char* qg = (const char*)(wq + (hb * LLEN + qt * 64) * KHEAD);
    const char* kg = (const char*)(wk + hb * LLEN * KHEAD);
    #pragma unroll
    for (int c = 0; c < 2; ++c)
        gload16(qg + c * 4096 + t * 16, (char*)qs + c * 4096 + wb);
    #pragma unroll
    for (int c = 0; c < 16; ++c)
        gload16(kg + c * 4096 + t * 16, (char*)ks + c * 4096 + wb);
    __syncthreads();

    const int l15 = lane & 15;
    const int g = lane >> 4;
    const int swz = (lane & 7) << 4;

    f32x4 acc[4][8];
    #pragma unroll
    for (int m = 0; m < 4; ++m)
        #pragma unroll
        for (int n = 0; n < 8; ++n)
            #pragma unroll
            for (int i = 0; i < 4; ++i) acc[m][n][i] = 0.f;

    #pragma unroll
    for (int kk = 0; kk < 2; ++kk) {
        bf16x8 af[4];
        #pragma unroll
        for (int m = 0; m < 4; ++m) {
            const int row = m * 16 + l15;
            af[m] = *(const bf16x8*)((const char*)qs + row * 128 + ((g * 16 + kk * 64) ^ swz));
        }
        #pragma unroll
        for (int n = 0; n < 8; ++n) {
            const int row = (w * 8 + n) * 16 + l15;
            const bf16x8 bfr = *(const bf16x8*)((const char*)ks + row * 128 + ((g * 16 + kk * 64) ^ swz));
            #pragma unroll
            for (int m = 0; m < 4; ++m)
                acc[m][n] = __builtin_amdgcn_mfma_f32_16x16x32_bf16(af[m], bfr, acc[m][n], 0, 0, 0);
        }
    }

    float rmax[4][4];
    #pragma unroll
    for (int m = 0; m < 4; ++m)
        #pragma unroll
        for (int i = 0; i < 4; ++i) {
            float mx = acc[m][0][i];
            #pragma unroll
            for (int n = 1; n < 8; ++n) mx = fmaxf(mx, acc[m][n][i]);
            mx = fmaxf(mx, __shfl_xor(mx, 1));
            mx = fmaxf(mx, __shfl_xor(mx, 2));
            mx = fmaxf(mx, __shfl_xor(mx, 4));
            mx = fmaxf(mx, __shfl_xor(mx, 8));
            if (l15 == 0) smax[w][m * 16 + g * 4 + i] = mx;
        }
    __syncthreads();
    #pragma unroll
    for (int m = 0; m < 4; ++m)
        #pragma unroll
        for (int i = 0; i < 4; ++i) {
            const int r = m * 16 + g * 4 + i;
            rmax[m][i] = fmaxf(fmaxf(smax[0][r], smax[1][r]),
                               fmaxf(smax[2][r], smax[3][r]));
        }
    float rinv[4][4];
    #pragma unroll
    for (int m = 0; m < 4; ++m)
        #pragma unroll
        for (int i = 0; i < 4; ++i) {
            float s = 0.f;
            #pragma unroll
            for (int n = 0; n < 8; ++n) {
                acc[m][n][i] = __expf(acc[m][n][i] - rmax[m][i]);
                s += acc[m][n][i];
            }
            s += __shfl_xor(s, 1); s += __shfl_xor(s, 2);
            s += __shfl_xor(s, 4); s += __shfl_xor(s, 8);
            if (l15 == 0) ssum[w][m * 16 + g * 4 + i] = s;
        }
    __syncthreads();
    #pragma unroll
    for (int m = 0; m < 4; ++m)
        #pragma unroll
        for (int i = 0; i < 4; ++i) {
            const int r = m * 16 + g * 4 + i;
            rinv[m][i] = 1.0f / (ssum[0][r] + ssum[1][r] + ssum[2][r] + ssum[3][r]);
        }

    u16* Pb = P + (hb * LLEN + qt * 64) * LLEN + w * 128;
    float cs[8];
    #pragma unroll
    for (int n = 0; n < 8; ++n) cs[n] = 0.f;
    #pragma unroll
    for (int m = 0; m < 4; ++m)
        #pragma unroll
        for (int i = 0; i < 4; ++i) {
            const int r = m * 16 + g * 4 + i;
            u16* pr = Pb + (long)r * LLEN + l15;
            const float iv = rinv[m][i];
            #pragma unroll
            for (int n = 0; n < 8; ++n) {
                const float p = acc[m][n][i] * iv;
                pr[n * 16] = f2bf(p);
                cs[n] += p;
            }
        }
    #pragma unroll
    for (int n = 0; n < 8; ++n) {
        cs[n] += __shfl_xor(cs[n], 16);
        cs[n] += __shfl_xor(cs[n], 32);
    }
    if (lane < 16) {
        float* cb = colsum + hb * 512 + w * 128 + lane;
        #pragma unroll
        for (int n = 0; n < 8; ++n) atomicAdd(&cb[n * 16], cs[n]);
    }
}

// Fused: preLN = o + hff @ W2^T + b2, LayerNorm, transpose-scatter fp32.
// Granule-XOR swizzled staging; tok = b*512 + l.
__global__ __launch_bounds__(256) void ffn2_ln(
    const u16* __restrict__ hff, const u16* __restrict__ W2bf,
    const float* __restrict__ b2, const u16* __restrict__ o,
    const float* __restrict__ lng, const float* __restrict__ lnb,
    float* __restrict__ out)
{
    __shared__ u16 W2s[512 * 64];
    __shared__ u16 hs[32 * 64];
    __shared__ float redS[4][32];
    __shared__ float redQ[4][32];

    const int h = blockIdx.z;
    const int m0 = blockIdx.x * 32;
    const int t = threadIdx.x;
    const int lane = t & 63, w = t >> 6;
    const int l15 = lane & 15, g = lane >> 4;
    const int wb = (t & 192) * 16;

    const char* w2g = (const char*)W2bf + (long)h * 65536;
    #pragma unroll
    for (int c = 0; c < 16; ++c) {
        const int idx = c * 4096 + t * 16;
        const int row = idx >> 7;
        const int g0 = (idx >> 4) & 7;
        gload16(w2g + row * 128 + ((g0 ^ (row & 7)) << 4),
                (char*)W2s + c * 4096 + wb);
    }
    {
        const int idx = t * 16;
        const int row = idx >> 7;
        const int g0 = (idx >> 4) & 7;
        gload16((const char*)(hff + ((long)h * NTOK + m0) * FFD) +
                    row * 128 + ((g0 ^ (row & 7)) << 4),
                (char*)hs + wb);
    }
    __syncthreads();

    f32x4 acc[2][8];
    #pragma unroll
    for (int m = 0; m < 2; ++m)
        #pragma unroll
        for (int n = 0; n < 8; ++n)
            #pragma unroll
            for (int i = 0; i < 4; ++i) acc[m][n][i] = 0.f;

    #pragma unroll
    for (int kk = 0; kk < 2; ++kk) {
        bf16x8 af[2];
        #pragma unroll
        for (int m = 0; m < 2; ++m) {
            const int row = m * 16 + l15;
            af[m] = *(const bf16x8*)((const char*)hs + row * 128 +
                                     (((kk * 4 + g) ^ (row & 7)) << 4));
        }
        #pragma unroll
        for (int n = 0; n < 8; ++n) {
            const int e = w * 128 + n * 16 + l15;
            const bf16x8 bfr = *(const bf16x8*)((const char*)W2s + e * 128 +
                                                (((kk * 4 + g) ^ (e & 7)) << 4));
            #pragma unroll
            for (int m = 0; m < 2; ++m)
                acc[m][n] = __builtin_amdgcn_mfma_f32_16x16x32_bf16(af[m], bfr, acc[m][n], 0, 0, 0);
        }
    }

    float b2v[8], gv[8], bv[8];
    #pragma unroll
    for (int n = 0; n < 8; ++n) {
        const int c = w * 128 + n * 16 + l15;
        b2v[n] = b2[h * DDIM + c];
        gv[n] = lng[h * DDIM + c];
        bv[n] = lnb[h * DDIM + c];
    }
    const u16* ob = o + ((long)h * NTOK + m0) * DDIM;
    #pragma unroll
    for (int m = 0; m < 2; ++m)
        #pragma unroll
        for (int i = 0; i < 4; ++i) {
            const int row = m * 16 + g * 4 + i;
            float s = 0.f, q = 0.f;
            #pragma unroll
            for (int n = 0; n < 8; ++n) {
                const int c = w * 128 + n * 16 + l15;
                const float v = acc[m][n][i] + b2v[n] + bf2f(ob[(long)row * DDIM + c]);
                acc[m][n][i] = v;
                s += v; q += v * v;
            }
            s += __shfl_xor(s, 1); q += __shfl_xor(q, 1);
            s += __shfl_xor(s, 2); q += __shfl_xor(q, 2);
            s += __shfl_xor(s, 4); q += __shfl_xor(q, 4);
            s += __shfl_xor(s, 8); q += __shfl_xor(q, 8);
            if (l15 == 0) { redS[w][row] = s; redQ[w][row] = q; }
        }
    __syncthreads();

    #pragma unroll
    for (int m = 0; m < 2; ++m)
        #pragma unroll
        for (int i = 0; i < 4; ++i) {
            const int row = m * 16 + g * 4 + i;
            const float s = redS[0][row] + redS[1][row] + redS[2][row] + redS[3][row];
            const float q = redQ[0][row] + redQ[1][row] + redQ[2][row] + redQ[3][row];
            const float mu = s * (1.0f / 512.0f);
            const float var = q * (1.0f / 512.0f) - mu * mu;
            const float rs = rsqrtf(var + 1e-5f);
            const int tok = m0 + row;
            const int b = tok >> 9, l = tok & 511;   // tok = b*512 + l
            float* op = out + ((long)(l * BBATCH + b)) * (HH * DDIM) + h * DDIM;
            #pragma unroll
            for (int n = 0; n < 8; ++n) {
                const int c = w * 128 + n * 16 + l15;
                op[c] = (acc[m][n][i] - mu) * rs * gv[n] + bv[n];
            }
        }
}

extern "C" void kernel_launch(void* const* d_in, const int* in_sizes, int n_in,
                              void* d_out, int out_size, void* d_ws, size_t ws_size,
                              hipStream_t stream) {
    const float* query = (const float*)d_in[0];
    const float* key   = (const float*)d_in[1];
    const float* value = (const float*)d_in[2];
    const float* WK = (const float*)d_in[3];
    const float* WQ = (const float*)d_in[4];
    const float* WV = (const float*)d_in[5];
    const float* Wt = (const float*)d_in[6];
    const float* W1 = (const float*)d_in[7];
    const float* b1 = (const float*)d_in[8];
    const float* W2 = (const float*)d_in[9];
    const float* b2 = (const float*)d_in[10];
    const float* lng = (const float*)d_in[11];
    const float* lnb = (const float*)d_in[12];

    // ---- workspace layout (bytes), peak 319,291,392 ----
    char* ws = (char*)d_ws;
    // [0,128MB): kbf/WQbf/WKbf until K1; P from attn_mfma
    u16* kbf  = (u16*)(ws);                    // 16 MB
    u16* WQbf = (u16*)(ws + 16777216);         // 0.5 MB
    u16* WKbf = (u16*)(ws + 17301504);         // 0.5 MB
    u16* P    = (u16*)(ws);                    // 128 MB
    // [128MB,256MB): vbf/WVbf until K2; o from K6
    u16* vbf  = (u16*)(ws + 134217728);        // 16 MB
    u16* WVbf = (u16*)(ws + 150994944);        // 0.5 MB
    u16* o    = (u16*)(ws + 134217728);        // 128 MB
    float* colsum = (float*)(ws + 268435456);  // 0.5 MB
    u16* qbf  = (u16*)(ws + 268959744);        // 16 MB, dead after K5
    u16* hff  = qbf;                           // overlay, produced at K7
    // wq/wk until attn_mfma; then Wt/W1/W2 bf16 into dead wq region
    u16* wq   = (u16*)(ws + 285736960);        // 16 MB
    u16* wk   = (u16*)(ws + 302514176);        // 16 MB
    u16* Wtbf = (u16*)(ws + 285736960);        // 4 MB
    u16* W1bf = (u16*)(ws + 289931264);        // 0.5 MB
    u16* W2bf = (u16*)(ws + 290455552);        // 0.5 MB
    // d_out doubles as scratch until ffn2_ln overwrites all of it:
    u16* qmo = (u16*)d_out;                        // [H][B][L][D]
    u16* wvT = (u16*)((char*)d_out + 134217728);   // [H][B][D][L]

    if (ws_size < 319291392u) return;

    hipMemsetAsync(colsum, 0, 524288, stream);
    const dim3 blk(256);

    // conv batch 1: inputs + QKV projection weights (6 jobs, one launch)
    {
        ConvJobs J;
        J.j[0] = { query, qbf, 2097152 };
        J.j[1] = { key,   kbf, 2097152 };
        J.j[2] = { value, vbf, 2097152 };
        J.j[3] = { WQ, WQbf, 65536 };
        J.j[4] = { WK, WKbf, 65536 };
        J.j[5] = { WV, WVbf, 524288 };
        J.nj = 6;
        conv_multi<<<dim3(2048), blk, 0, stream>>>(J);
    }

    // K1: wq/wk = l2norm(query/key @ WQ/WK^T) -> [H,B,L,K] bf16 (swizzled rows)
    mgemm<128, 128, M_WQK, 0, 1><<<dim3(4, 128, 1), blk, 0, stream>>>(
        qbf, WQbf, wq, 512, 512, 512, 0,
        0, 0, 0, 0, 0, 0, 1, nullptr, 0, nullptr, 0, 0, 0);
    mgemm<128, 128, M_WQK, 0, 1><<<dim3(4, 128, 1), blk, 0, stream>>>(
        kbf, WKbf, wk, 512, 512, 512, 0,
        0, 0, 0, 0, 0, 0, 1, nullptr, 0, nullptr, 0, 0, 0);

    // attn: softmax(QK^T) -> P + colsum, one pass, XCD-aware grid
    attn_mfma<<<dim3(2048), blk, 0, stream>>>(wq, wk, P, colsum);

    // conv batch 2: FFN weights into the now-dead wq region (one launch)
    {
        ConvJobs J;
        J.j[0] = { Wt, Wtbf, 524288 };
        J.j[1] = { W1, W1bf, 65536 };
        J.j[2] = { W2, W2bf, 65536 };
        J.nj = 3;
        conv_multi<<<dim3(1024), blk, 0, stream>>>(J);
    }

    // K2: wvT[h,b,e,l] = (WV @ value^T) / (1e-9 + colsum[h,b,l])
    mgemm<128, 128, M_SCALECOL, 2, 0><<<dim3(4, 4, 256), blk, 0, stream>>>(
        WVbf, vbf, wvT, 512, 512, BBATCH * DDIM, 512,
        (long)DDIM * DDIM, 0, 0, DDIM,
        (long)BBATCH * DDIM * LLEN, (long)DDIM * LLEN, 32,
        nullptr, 0, colsum, (long)BBATCH * 512, 512, 0);

    // K5: qmo = query - P @ wvT^T   (b-major z: qbf rows L2-reused across h)
    mgemm<128, 128, M_SUBAUX, 1, 0><<<dim3(4, 4, 256), blk, 0, stream>>>(
        P, wvT, qmo, 512, 512, 512, 512,
        (long)BBATCH * LLEN * LLEN, (long)LLEN * LLEN,
        (long)BBATCH * DDIM * LLEN, (long)DDIM * LLEN,
        (long)BBATCH * LLEN * DDIM, (long)LLEN * DDIM, 32,
        nullptr, 0, qbf, 0, DDIM, BBATCH * DDIM);

    // K6: o = relu(qmo @ Wt^T)   (SWAPXY: qmo fetched ~once, Wt L2-resident)
    mgemm<128, 128, M_RELU, 0, 1><<<dim3(4, 128, 8), blk, 0, stream>>>(
        qmo, Wtbf, o, 512, 512, 512, 512,
        (long)NTOK * DDIM, 0, (long)DDIM * DDIM, 0,
        (long)NTOK * DDIM, 0, 1, nullptr, 512, nullptr, 0, 0, 0);

    // K7: hff = relu(o @ W1^T + b1)   (BN=64)
    mgemm<128, 64, M_RELU, 0, 0><<<dim3(128, 1, 8), blk, 0, stream>>>(
        o, W1bf, hff, 512, 512, 512, 64,
        (long)NTOK * DDIM, 0, (long)FFD * DDIM, 0,
        (long)NTOK * FFD, 0, 1, b1, 64, nullptr, 0, 0, 0);

    // K8 + LN + transpose fused
    ffn2_ln<<<dim3(512, 1, 8), blk, 0, stream>>>(hff, W2bf, b2, o, lng, lnb,
                                                 (float*)d_out);
}

// Round 13
// 762.708 us; speedup vs baseline: 1.0803x; 1.0046x over previous
//
#include <hip/hip_runtime.h>
#include <stdint.h>

#define HH 8
#define DDIM 512
#define KHEAD 64
#define FFD 64
#define LLEN 512
#define BBATCH 32
#define NTOK 16384  // L*B

typedef unsigned short u16;
typedef __attribute__((ext_vector_type(8))) __bf16 bf16x8;
typedef __attribute__((ext_vector_type(4))) float f32x4;

__device__ __forceinline__ float bf2f(u16 u) {
    union { uint32_t i; float f; } v; v.i = ((uint32_t)u) << 16; return v.f;
}
__device__ __forceinline__ u16 f2bf(float f) {
    union { uint32_t i; float f; } v; v.f = f;
    return (u16)((v.i + 0x7FFFu + ((v.i >> 16) & 1u)) >> 16);
}

__device__ __forceinline__ void gload16(const void* g, void* l) {
    __builtin_amdgcn_global_load_lds(
        (const __attribute__((address_space(1))) void*)g,
        (__attribute__((address_space(3))) void*)l, 16, 0, 0);
}

// ---- fused fp32->bf16 conversion: several tensors in one launch ----
struct ConvJob { const float* s; u16* d; int n4; };
struct ConvJobs { ConvJob j[6]; int nj; };

__global__ __launch_bounds__(256) void conv_multi(ConvJobs jobs) {
    for (int k = 0; k < jobs.nj; ++k) {
        const float* s = jobs.j[k].s;
        u16* d = jobs.j[k].d;
        const int n4 = jobs.j[k].n4;
        for (long i = (long)blockIdx.x * 256 + threadIdx.x; i < n4;
             i += (long)gridDim.x * 256) {
            float4 v = ((const float4*)s)[i];
            ushort4 o;
            o.x = f2bf(v.x); o.y = f2bf(v.y); o.z = f2bf(v.z); o.w = f2bf(v.w);
            ((ushort4*)d)[i] = o;
        }
    }
}

enum { M_PLAIN = 0, M_WQK = 1, M_SUBAUX = 2, M_RELU = 3, M_ADDAUX = 4, M_SCALECOL = 5 };

// MFMA batched GEMM. Round-12 structure with ONE change: 3-buffer pipeline
// with counted s_waitcnt vmcnt(2*NLD) -> 2 staging batches stay in flight
// across the barriers (T4). Staging layout / fragment reads / epilogues
// are byte-identical to round 12.
template<int BM, int BN, int MODE, int ZMAP, int SWAPXY>
__global__ __launch_bounds__(256) void mgemm(
    const u16* __restrict__ A, const u16* __restrict__ B, u16* __restrict__ C,
    int Kd, int lda, int ldb, int ldc,
    long Ash, long Asb, long Bsh, long Bsb, long Csh, long Csb, int nB2,
    const float* __restrict__ bias, int biasN,
    const void* __restrict__ auxp, long auxsh, long auxsb, int auxld)
{
    constexpr int WC = (BN == 128) ? 2 : 1;
    constexpr int WR = 4 / WC;
    constexpr int WTM = BM / WR;
    constexpr int WTN = BN / WC;
    constexpr int MF = WTM / 16;
    constexpr int NF = WTN / 16;
    constexpr int NCA = (BM * 64) / 4096;
    constexpr int NCB = (BN * 64) / 4096;
    constexpr int NLD = NCA + NCB;      // global_load_lds per stage per thread
    __shared__ u16 As[3][BM * 32];
    __shared__ u16 Bs[3][BN * 32];

    const int z = blockIdx.z;
    int h2, b2;
    if (ZMAP == 0)      { h2 = z / nB2;      b2 = z % nB2; }
    else if (ZMAP == 1) { h2 = z & 7;        b2 = z >> 3; }
    else                { h2 = (z >> 3) & 7; b2 = ((z >> 6) << 3) | (z & 7); }
    const u16* Ab = A + h2 * Ash + b2 * Asb;
    const u16* Bb = B + h2 * Bsh + b2 * Bsb;
    const int bx = SWAPXY ? blockIdx.y : blockIdx.x;
    const int by = SWAPXY ? blockIdx.x : blockIdx.y;
    const int m0 = bx * BM, n0 = by * BN;
    const int t = threadIdx.x;
    const int lane = t & 63;
    const int w = t >> 6;
    const int wr = w / WC, wc = w % WC;
    const int tb = t * 16;
    const int wb = (t & 192) * 16;

    f32x4 acc[MF][NF];
    #pragma unroll
    for (int m = 0; m < MF; ++m)
        #pragma unroll
        for (int n = 0; n < NF; ++n)
            #pragma unroll
            for (int i = 0; i < 4; ++i) acc[m][n][i] = 0.f;

    const int ko = (lane >> 4) * 16;

    auto stage = [&](int buf, int k0) {
        #pragma unroll
        for (int c = 0; c < NCA; ++c) {
            const int byte = c * 4096 + tb;
            const int row = byte >> 6;
            gload16((const char*)(Ab + (long)(m0 + row) * lda + k0) + (byte & 63),
                    (char*)As[buf] + c * 4096 + wb);
        }
        #pragma unroll
        for (int c = 0; c < NCB; ++c) {
            const int byte = c * 4096 + tb;
            const int row = byte >> 6;
            gload16((const char*)(Bb + (long)(n0 + row) * ldb + k0) + (byte & 63),
                    (char*)Bs[buf] + c * 4096 + wb);
        }
    };

    const int nsteps = Kd >> 5;          // 16 for all current calls
    stage(0, 0);
    if (nsteps > 1) stage(1, 32);
    if (nsteps > 2) stage(2, 64);

    int cur = 0;
    for (int s = 0; s < nsteps; ++s) {
        // wait for stage s only; stages s+1, s+2 stay in flight (T4)
        if (s + 2 < nsteps) {
            if constexpr (NLD == 4) asm volatile("s_waitcnt vmcnt(8)" ::: "memory");
            else                    asm volatile("s_waitcnt vmcnt(6)" ::: "memory");
        } else if (s + 1 < nsteps) {
            if constexpr (NLD == 4) asm volatile("s_waitcnt vmcnt(4)" ::: "memory");
            else                    asm volatile("s_waitcnt vmcnt(3)" ::: "memory");
        } else {
            asm volatile("s_waitcnt vmcnt(0)" ::: "memory");
        }
        __builtin_amdgcn_sched_barrier(0);
        __builtin_amdgcn_s_barrier();        // buf[cur] fully populated
        __builtin_amdgcn_sched_barrier(0);

        bf16x8 af[MF], bfr[NF];
        #pragma unroll
        for (int m = 0; m < MF; ++m)
            af[m] = *(const bf16x8*)((const char*)As[cur] + (wr * WTM + m * 16 + (lane & 15)) * 64 + ko);
        #pragma unroll
        for (int n = 0; n < NF; ++n)
            bfr[n] = *(const bf16x8*)((const char*)Bs[cur] + (wc * WTN + n * 16 + (lane & 15)) * 64 + ko);
        #pragma unroll
        for (int m = 0; m < MF; ++m)
            #pragma unroll
            for (int n = 0; n < NF; ++n)
                acc[m][n] = __builtin_amdgcn_mfma_f32_16x16x32_bf16(af[m], bfr[n], acc[m][n], 0, 0, 0);

        __builtin_amdgcn_sched_barrier(0);
        __builtin_amdgcn_s_barrier();        // all waves done reading buf[cur]
        __builtin_amdgcn_sched_barrier(0);
        if (s + 3 < nsteps) stage(cur, (s + 3) << 5);   // overwrite freed buf
        cur = (cur == 2) ? 0 : cur + 1;
    }

    const int lr = (lane >> 4) * 4;
    const int lc = lane & 15;

    if constexpr (MODE == M_WQK) {
        const int h = (n0 + wc * WTN) >> 6;
        #pragma unroll
        for (int m = 0; m < MF; ++m) {
            #pragma unroll
            for (int i = 0; i < 4; ++i) {
                float s = 0.f;
                #pragma unroll
                for (int n = 0; n < NF; ++n) { const float v = acc[m][n][i]; s += v * v; }
                s += __shfl_xor(s, 1); s += __shfl_xor(s, 2);
                s += __shfl_xor(s, 4); s += __shfl_xor(s, 8);
                const float inv = 1.0f / fmaxf(sqrtf(s), 1e-12f);
                const int r = m0 + wr * WTM + m * 16 + lr + i;  // token = l*B + b
                const int l = r >> 5, bq = r & 31;
                const int sw = (l & 7) << 3;
                u16* rowp = C + (((long)(h * BBATCH + bq) * LLEN + l) * KHEAD);
                #pragma unroll
                for (int n = 0; n < NF; ++n)
                    rowp[(lc + n * 16) ^ sw] = f2bf(acc[m][n][i] * inv);
            }
        }
    } else {
        const long cof = h2 * Csh + b2 * Csb;
        #pragma unroll
        for (int m = 0; m < MF; ++m) {
            #pragma unroll
            for (int i = 0; i < 4; ++i) {
                const int r = m0 + wr * WTM + m * 16 + lr + i;
                #pragma unroll
                for (int n = 0; n < NF; ++n) {
                    const int c = n0 + wc * WTN + n * 16 + lc;
                    float v = acc[m][n][i];
                    if (MODE == M_SUBAUX) {
                        const u16* q = (const u16*)auxp;
                        v = bf2f(q[auxsh * h2 + auxsb * b2 + (long)r * auxld + c]) - v;
                    } else if (MODE == M_RELU) {
                        if (bias) v += bias[h2 * biasN + c];
                        v = fmaxf(v, 0.0f);
                    } else if (MODE == M_ADDAUX) {
                        v += bias[h2 * biasN + c];
                        const u16* ax = (const u16*)auxp;
                        v += bf2f(ax[auxsh * h2 + auxsb * b2 + (long)r * auxld + c]);
                    } else if (MODE == M_SCALECOL) {
                        const float* cs = (const float*)auxp + auxsh * h2 + auxsb * b2;
                        v *= 1.0f / (1e-9f + cs[c]);
                    }
                    C[cof + (long)r * ldc + c] = f2bf(v);
                }
            }
        }
    }
}

// XCD-aware decode: 8 qt-blocks of one (h,b) -> same wgid%8 (same XCD).
__device__ __forceinline__ void xcd_decode(int wgid, int& qt, int& b, int& h) {
    const int r = wgid & 7;
    const int inner = wgid >> 3;
    qt = inner & 7;
    h = (inner >> 3) & 7;
    b = ((inner >> 6) << 3) | r;
}

// MFMA QK^T + softmax -> P (bf16) + column sums (fp32 atomics).
__global__ __launch_bounds__(256) void attn_mfma(
    const u16* __restrict__ wq, const u16* __restrict__ wk,
    u16* __restrict__ P, float* __restrict__ colsum)
{
    __shared__ u16 qs[64 * 64];
    __shared__ u16 ks[512 * 64];
    __shared__ float smax[4][64];
    __shared__ float ssum[4][64];

    int qt, b, h;
    xcd_decode(blockIdx.x, qt, b, h);
    const long hb = h * BBATCH + b;
    const int t = threadIdx.x;
    const int lane = t & 63, w = t >> 6;
    const int wb = (t & 192) * 16;

    const char* qg = (const char*)(wq + (hb * LLEN + qt * 64) * KHEAD);
    const char* kg = (const char*)(wk + hb * LLEN * KHEAD);
    #pragma unroll
    for (int c = 0; c < 2; ++c)
        gload16(qg + c * 4096 + t * 16, (char*)qs + c * 4096 + wb);
    #pragma unroll
    for (int c = 0; c < 16; ++c)
        gload16(kg + c * 4096 + t * 16, (char*)ks + c * 4096 + wb);
    __syncthreads();

    const int l15 = lane & 15;
    const int g = lane >> 4;
    const int swz = (lane & 7) << 4;

    f32x4 acc[4][8];
    #pragma unroll
    for (int m = 0; m < 4; ++m)
        #pragma unroll
        for (int n = 0; n < 8; ++n)
            #pragma unroll
            for (int i = 0; i < 4; ++i) acc[m][n][i] = 0.f;

    #pragma unroll
    for (int kk = 0; kk < 2; ++kk) {
        bf16x8 af[4];
        #pragma unroll
        for (int m = 0; m < 4; ++m) {
            const int row = m * 16 + l15;
            af[m] = *(const bf16x8*)((const char*)qs + row * 128 + ((g * 16 + kk * 64) ^ swz));
        }
        #pragma unroll
        for (int n = 0; n < 8; ++n) {
            const int row = (w * 8 + n) * 16 + l15;
            const bf16x8 bfr = *(const bf16x8*)((const char*)ks + row * 128 + ((g * 16 + kk * 64) ^ swz));
            #pragma unroll
            for (int m = 0; m < 4; ++m)
                acc[m][n] = __builtin_amdgcn_mfma_f32_16x16x32_bf16(af[m], bfr, acc[m][n], 0, 0, 0);
        }
    }

    float rmax[4][4];
    #pragma unroll
    for (int m = 0; m < 4; ++m)
        #pragma unroll
        for (int i = 0; i < 4; ++i) {
            float mx = acc[m][0][i];
            #pragma unroll
            for (int n = 1; n < 8; ++n) mx = fmaxf(mx, acc[m][n][i]);
            mx = fmaxf(mx, __shfl_xor(mx, 1));
            mx = fmaxf(mx, __shfl_xor(mx, 2));
            mx = fmaxf(mx, __shfl_xor(mx, 4));
            mx = fmaxf(mx, __shfl_xor(mx, 8));
            if (l15 == 0) smax[w][m * 16 + g * 4 + i] = mx;
        }
    __syncthreads();
    #pragma unroll
    for (int m = 0; m < 4; ++m)
        #pragma unroll
        for (int i = 0; i < 4; ++i) {
            const int r = m * 16 + g * 4 + i;
            rmax[m][i] = fmaxf(fmaxf(smax[0][r], smax[1][r]),
                               fmaxf(smax[2][r], smax[3][r]));
        }
    float rinv[4][4];
    #pragma unroll
    for (int m = 0; m < 4; ++m)
        #pragma unroll
        for (int i = 0; i < 4; ++i) {
            float s = 0.f;
            #pragma unroll
            for (int n = 0; n < 8; ++n) {
                acc[m][n][i] = __expf(acc[m][n][i] - rmax[m][i]);
                s += acc[m][n][i];
            }
            s += __shfl_xor(s, 1); s += __shfl_xor(s, 2);
            s += __shfl_xor(s, 4); s += __shfl_xor(s, 8);
            if (l15 == 0) ssum[w][m * 16 + g * 4 + i] = s;
        }
    __syncthreads();
    #pragma unroll
    for (int m = 0; m < 4; ++m)
        #pragma unroll
        for (int i = 0; i < 4; ++i) {
            const int r = m * 16 + g * 4 + i;
            rinv[m][i] = 1.0f / (ssum[0][r] + ssum[1][r] + ssum[2][r] + ssum[3][r]);
        }

    u16* Pb = P + (hb * LLEN + qt * 64) * LLEN + w * 128;
    float cs[8];
    #pragma unroll
    for (int n = 0; n < 8; ++n) cs[n] = 0.f;
    #pragma unroll
    for (int m = 0; m < 4; ++m)
        #pragma unroll
        for (int i = 0; i < 4; ++i) {
            const int r = m * 16 + g * 4 + i;
            u16* pr = Pb + (long)r * LLEN + l15;
            const float iv = rinv[m][i];
            #pragma unroll
            for (int n = 0; n < 8; ++n) {
                const float p = acc[m][n][i] * iv;
                pr[n * 16] = f2bf(p);
                cs[n] += p;
            }
        }
    #pragma unroll
    for (int n = 0; n < 8; ++n) {
        cs[n] += __shfl_xor(cs[n], 16);
        cs[n] += __shfl_xor(cs[n], 32);
    }
    if (lane < 16) {
        float* cb = colsum + hb * 512 + w * 128 + lane;
        #pragma unroll
        for (int n = 0; n < 8; ++n) atomicAdd(&cb[n * 16], cs[n]);
    }
}

// Fused: preLN = o + hff @ W2^T + b2, LayerNorm, transpose-scatter fp32.
__global__ __launch_bounds__(256) void ffn2_ln(
    const u16* __restrict__ hff, const u16* __restrict__ W2bf,
    const float* __restrict__ b2, const u16* __restrict__ o,
    const float* __restrict__ lng, const float* __restrict__ lnb,
    float* __restrict__ out)
{
    __shared__ u16 W2s[512 * 64];
    __shared__ u16 hs[32 * 64];
    __shared__ float redS[4][32];
    __shared__ float redQ[4][32];

    const int h = blockIdx.z;
    const int m0 = blockIdx.x * 32;
    const int t = threadIdx.x;
    const int lane = t & 63, w = t >> 6;
    const int l15 = lane & 15, g = lane >> 4;
    const int wb = (t & 192) * 16;

    const char* w2g = (const char*)W2bf + (long)h * 65536;
    #pragma unroll
    for (int c = 0; c < 16; ++c) {
        const int idx = c * 4096 + t * 16;
        const int row = idx >> 7;
        const int g0 = (idx >> 4) & 7;
        gload16(w2g + row * 128 + ((g0 ^ (row & 7)) << 4),
                (char*)W2s + c * 4096 + wb);
    }
    {
        const int idx = t * 16;
        const int row = idx >> 7;
        const int g0 = (idx >> 4) & 7;
        gload16((const char*)(hff + ((long)h * NTOK + m0) * FFD) +
                    row * 128 + ((g0 ^ (row & 7)) << 4),
                (char*)hs + wb);
    }
    __syncthreads();

    f32x4 acc[2][8];
    #pragma unroll
    for (int m = 0; m < 2; ++m)
        #pragma unroll
        for (int n = 0; n < 8; ++n)
            #pragma unroll
            for (int i = 0; i < 4; ++i) acc[m][n][i] = 0.f;

    #pragma unroll
    for (int kk = 0; kk < 2; ++kk) {
        bf16x8 af[2];
        #pragma unroll
        for (int m = 0; m < 2; ++m) {
            const int row = m * 16 + l15;
            af[m] = *(const bf16x8*)((const char*)hs + row * 128 +
                                     (((kk * 4 + g) ^ (row & 7)) << 4));
        }
        #pragma unroll
        for (int n = 0; n < 8; ++n) {
            const int e = w * 128 + n * 16 + l15;
            const bf16x8 bfr = *(const bf16x8*)((const char*)W2s + e * 128 +
                                                (((kk * 4 + g) ^ (e & 7)) << 4));
            #pragma unroll
            for (int m = 0; m < 2; ++m)
                acc[m][n] = __builtin_amdgcn_mfma_f32_16x16x32_bf16(af[m], bfr, acc[m][n], 0, 0, 0);
        }
    }

    float b2v[8], gv[8], bv[8];
    #pragma unroll
    for (int n = 0; n < 8; ++n) {
        const int c = w * 128 + n * 16 + l15;
        b2v[n] = b2[h * DDIM + c];
        gv[n] = lng[h * DDIM + c];
        bv[n] = lnb[h * DDIM + c];
    }
    const u16* ob = o + ((long)h * NTOK + m0) * DDIM;
    #pragma unroll
    for (int m = 0; m < 2; ++m)
        #pragma unroll
        for (int i = 0; i < 4; ++i) {
            const int row = m * 16 + g * 4 + i;
            float s = 0.f, q = 0.f;
            #pragma unroll
            for (int n = 0; n < 8; ++n) {
                const int c = w * 128 + n * 16 + l15;
                const float v = acc[m][n][i] + b2v[n] + bf2f(ob[(long)row * DDIM + c]);
                acc[m][n][i] = v;
                s += v; q += v * v;
            }
            s += __shfl_xor(s, 1); q += __shfl_xor(q, 1);
            s += __shfl_xor(s, 2); q += __shfl_xor(q, 2);
            s += __shfl_xor(s, 4); q += __shfl_xor(q, 4);
            s += __shfl_xor(s, 8); q += __shfl_xor(q, 8);
            if (l15 == 0) { redS[w][row] = s; redQ[w][row] = q; }
        }
    __syncthreads();

    #pragma unroll
    for (int m = 0; m < 2; ++m)
        #pragma unroll
        for (int i = 0; i < 4; ++i) {
            const int row = m * 16 + g * 4 + i;
            const float s = redS[0][row] + redS[1][row] + redS[2][row] + redS[3][row];
            const float q = redQ[0][row] + redQ[1][row] + redQ[2][row] + redQ[3][row];
            const float mu = s * (1.0f / 512.0f);
            const float var = q * (1.0f / 512.0f) - mu * mu;
            const float rs = rsqrtf(var + 1e-5f);
            const int tok = m0 + row;
            const int b = tok >> 9, l = tok & 511;   // tok = b*512 + l
            float* op = out + ((long)(l * BBATCH + b)) * (HH * DDIM) + h * DDIM;
            #pragma unroll
            for (int n = 0; n < 8; ++n) {
                const int c = w * 128 + n * 16 + l15;
                op[c] = (acc[m][n][i] - mu) * rs * gv[n] + bv[n];
            }
        }
}

extern "C" void kernel_launch(void* const* d_in, const int* in_sizes, int n_in,
                              void* d_out, int out_size, void* d_ws, size_t ws_size,
                              hipStream_t stream) {
    const float* query = (const float*)d_in[0];
    const float* key   = (const float*)d_in[1];
    const float* value = (const float*)d_in[2];
    const float* WK = (const float*)d_in[3];
    const float* WQ = (const float*)d_in[4];
    const float* WV = (const float*)d_in[5];
    const float* Wt = (const float*)d_in[6];
    const float* W1 = (const float*)d_in[7];
    const float* b1 = (const float*)d_in[8];
    const float* W2 = (const float*)d_in[9];
    const float* b2 = (const float*)d_in[10];
    const float* lng = (const float*)d_in[11];
    const float* lnb = (const float*)d_in[12];

    // ---- workspace layout (bytes), peak 319,291,392 ----
    char* ws = (char*)d_ws;
    u16* kbf  = (u16*)(ws);                    // 16 MB
    u16* WQbf = (u16*)(ws + 16777216);         // 0.5 MB
    u16* WKbf = (u16*)(ws + 17301504);         // 0.5 MB
    u16* P    = (u16*)(ws);                    // 128 MB
    u16* vbf  = (u16*)(ws + 134217728);        // 16 MB
    u16* WVbf = (u16*)(ws + 150994944);        // 0.5 MB
    u16* o    = (u16*)(ws + 134217728);        // 128 MB (from K6)
    float* colsum = (float*)(ws + 268435456);  // 0.5 MB
    u16* qbf  = (u16*)(ws + 268959744);        // 16 MB, dead after K5
    u16* hff  = qbf;                           // overlay, produced at K7
    u16* wq   = (u16*)(ws + 285736960);        // 16 MB
    u16* wk   = (u16*)(ws + 302514176);        // 16 MB
    u16* Wtbf = (u16*)(ws + 285736960);        // 4 MB (into dead wq)
    u16* W1bf = (u16*)(ws + 289931264);        // 0.5 MB
    u16* W2bf = (u16*)(ws + 290455552);        // 0.5 MB
    u16* qmo = (u16*)d_out;                        // [H][B][L][D]
    u16* wvT = (u16*)((char*)d_out + 134217728);   // [H][B][D][L]

    if (ws_size < 319291392u) return;

    hipMemsetAsync(colsum, 0, 524288, stream);
    const dim3 blk(256);

    // conv batch 1: inputs + QKV projection weights
    {
        ConvJobs J;
        J.j[0] = { query, qbf, 2097152 };
        J.j[1] = { key,   kbf, 2097152 };
        J.j[2] = { value, vbf, 2097152 };
        J.j[3] = { WQ, WQbf, 65536 };
        J.j[4] = { WK, WKbf, 65536 };
        J.j[5] = { WV, WVbf, 524288 };
        J.nj = 6;
        conv_multi<<<dim3(2048), blk, 0, stream>>>(J);
    }

    // K1: wq/wk = l2norm(query/key @ WQ/WK^T) -> [H,B,L,K] bf16 (swizzled rows)
    mgemm<128, 128, M_WQK, 0, 1><<<dim3(4, 128, 1), blk, 0, stream>>>(
        qbf, WQbf, wq, 512, 512, 512, 0,
        0, 0, 0, 0, 0, 0, 1, nullptr, 0, nullptr, 0, 0, 0);
    mgemm<128, 128, M_WQK, 0, 1><<<dim3(4, 128, 1), blk, 0, stream>>>(
        kbf, WKbf, wk, 512, 512, 512, 0,
        0, 0, 0, 0, 0, 0, 1, nullptr, 0, nullptr, 0, 0, 0);

    // attn: softmax(QK^T) -> P + colsum, XCD-aware grid
    attn_mfma<<<dim3(2048), blk, 0, stream>>>(wq, wk, P, colsum);

    // conv batch 2: FFN weights into the now-dead wq region
    {
        ConvJobs J;
        J.j[0] = { Wt, Wtbf, 524288 };
        J.j[1] = { W1, W1bf, 65536 };
        J.j[2] = { W2, W2bf, 65536 };
        J.nj = 3;
        conv_multi<<<dim3(1024), blk, 0, stream>>>(J);
    }

    // K2: wvT[h,b,e,l] = (WV @ value^T) / (1e-9 + colsum[h,b,l])
    mgemm<128, 128, M_SCALECOL, 2, 0><<<dim3(4, 4, 256), blk, 0, stream>>>(
        WVbf, vbf, wvT, 512, 512, BBATCH * DDIM, 512,
        (long)DDIM * DDIM, 0, 0, DDIM,
        (long)BBATCH * DDIM * LLEN, (long)DDIM * LLEN, 32,
        nullptr, 0, colsum, (long)BBATCH * 512, 512, 0);

    // K5: qmo = query - P @ wvT^T   (b-major z: qbf rows L2-reused across h)
    mgemm<128, 128, M_SUBAUX, 1, 0><<<dim3(4, 4, 256), blk, 0, stream>>>(
        P, wvT, qmo, 512, 512, 512, 512,
        (long)BBATCH * LLEN * LLEN, (long)LLEN * LLEN,
        (long)BBATCH * DDIM * LLEN, (long)DDIM * LLEN,
        (long)BBATCH * LLEN * DDIM, (long)LLEN * DDIM, 32,
        nullptr, 0, qbf, 0, DDIM, BBATCH * DDIM);

    // K6: o = relu(qmo @ Wt^T)
    mgemm<128, 128, M_RELU, 0, 1><<<dim3(4, 128, 8), blk, 0, stream>>>(
        qmo, Wtbf, o, 512, 512, 512, 512,
        (long)NTOK * DDIM, 0, (long)DDIM * DDIM, 0,
        (long)NTOK * DDIM, 0, 1, nullptr, 512, nullptr, 0, 0, 0);

    // K7: hff = relu(o @ W1^T + b1)   (BN=64)
    mgemm<128, 64, M_RELU, 0, 0><<<dim3(128, 1, 8), blk, 0, stream>>>(
        o, W1bf, hff, 512, 512, 512, 64,
        (long)NTOK * DDIM, 0, (long)FFD * DDIM, 0,
        (long)NTOK * FFD, 0, 1, b1, 64, nullptr, 0, 0, 0);

    // K8 + LN + transpose fused
    ffn2_ln<<<dim3(512, 1, 8), blk, 0, stream>>>(hff, W2bf, b2, o, lng, lnb,
                                                 (float*)d_out);
}

// Round 14
// 744.608 us; speedup vs baseline: 1.1065x; 1.0243x over previous
//
#include <hip/hip_runtime.h>
#include <stdint.h>

#define HH 8
#define DDIM 512
#define KHEAD 64
#define FFD 64
#define LLEN 512
#define BBATCH 32
#define NTOK 16384  // L*B

typedef unsigned short u16;
typedef __attribute__((ext_vector_type(8))) __bf16 bf16x8;
typedef __attribute__((ext_vector_type(4))) float f32x4;

__device__ __forceinline__ float bf2f(u16 u) {
    union { uint32_t i; float f; } v; v.i = ((uint32_t)u) << 16; return v.f;
}
__device__ __forceinline__ u16 f2bf(float f) {
    union { uint32_t i; float f; } v; v.f = f;
    return (u16)((v.i + 0x7FFFu + ((v.i >> 16) & 1u)) >> 16);
}

__device__ __forceinline__ void gload16(const void* g, void* l) {
    __builtin_amdgcn_global_load_lds(
        (const __attribute__((address_space(1))) void*)g,
        (__attribute__((address_space(3))) void*)l, 16, 0, 0);
}

// ---- fused fp32->bf16 conversion ----
struct ConvJob { const float* s; u16* d; int n4; };
struct ConvJobs { ConvJob j[6]; int nj; };

__global__ __launch_bounds__(256) void conv_multi(ConvJobs jobs) {
    for (int k = 0; k < jobs.nj; ++k) {
        const float* s = jobs.j[k].s;
        u16* d = jobs.j[k].d;
        const int n4 = jobs.j[k].n4;
        for (long i = (long)blockIdx.x * 256 + threadIdx.x; i < n4;
             i += (long)gridDim.x * 256) {
            float4 v = ((const float4*)s)[i];
            ushort4 o;
            o.x = f2bf(v.x); o.y = f2bf(v.y); o.z = f2bf(v.z); o.w = f2bf(v.w);
            ((ushort4*)d)[i] = o;
        }
    }
}

enum { M_PLAIN = 0, M_WQK = 1, M_SUBAUX = 2, M_RELU = 3, M_ADDAUX = 4, M_SCALECOL = 5 };

// ---------------------------------------------------------------------------
// 256x256-tile MFMA GEMM, BK=64, 512 threads (8 waves, 2M x 4N).
// One s_barrier per K-tile; LDS granule-XOR swizzle (slot g0 of row r holds
// global granule g0^(r&7); source permutation stays within one 128B line so
// global coalescing is preserved). setprio(1) around MFMA quadrants.
// ---------------------------------------------------------------------------
template<int MODE, int ZMAP, int SWAPXY>
__global__ __launch_bounds__(512) void mgemm256(
    const u16* __restrict__ A, const u16* __restrict__ B, u16* __restrict__ C,
    int Kd, int lda, int ldb, int ldc,
    long Ash, long Asb, long Bsh, long Bsb, long Csh, long Csb, int nB2,
    const float* __restrict__ bias, int biasN,
    const void* __restrict__ auxp, long auxsh, long auxsb, int auxld)
{
    __shared__ u16 As[2][256 * 64];   // 32 KB per buffer
    __shared__ u16 Bs[2][256 * 64];   // total 128 KB

    const int z = blockIdx.z;
    int h2, b2;
    if (ZMAP == 0)      { h2 = z / nB2;      b2 = z % nB2; }
    else if (ZMAP == 1) { h2 = z & 7;        b2 = z >> 3; }
    else                { h2 = (z >> 3) & 7; b2 = ((z >> 6) << 3) | (z & 7); }
    const int bx = SWAPXY ? blockIdx.y : blockIdx.x;
    const int by = SWAPXY ? blockIdx.x : blockIdx.y;
    const int m0 = bx * 256, n0 = by * 256;
    const u16* Ab = A + h2 * Ash + b2 * Asb + (long)m0 * lda;
    const u16* Bb = B + h2 * Bsh + b2 * Bsb + (long)n0 * ldb;

    const int t = threadIdx.x;
    const int lane = t & 63;
    const int w = t >> 6;          // 0..7
    const int wm = w >> 2;         // 0..1 (row half)
    const int wn = w & 3;          // 0..3 (col quarter)
    const int l15 = lane & 15;
    const int g = lane >> 4;       // 0..3

    f32x4 acc[8][4];
    #pragma unroll
    for (int mf = 0; mf < 8; ++mf)
        #pragma unroll
        for (int nf = 0; nf < 4; ++nf)
            #pragma unroll
            for (int i = 0; i < 4; ++i) acc[mf][nf][i] = 0.f;

    auto stageT = [&](int buf, int k0) {
        #pragma unroll
        for (int c = 0; c < 4; ++c) {
            const int idx = c * 8192 + t * 16;
            const int row = idx >> 7;
            const int g0 = (idx >> 4) & 7;
            gload16((const char*)(Ab + (long)row * lda + k0) + ((g0 ^ (row & 7)) << 4),
                    (char*)As[buf] + c * 8192 + w * 1024);
        }
        #pragma unroll
        for (int c = 0; c < 4; ++c) {
            const int idx = c * 8192 + t * 16;
            const int row = idx >> 7;
            const int g0 = (idx >> 4) & 7;
            gload16((const char*)(Bb + (long)row * ldb + k0) + ((g0 ^ (row & 7)) << 4),
                    (char*)Bs[buf] + c * 8192 + w * 1024);
        }
    };

    stageT(0, 0);
    const int nt = Kd >> 6;
    for (int T = 0; T < nt; ++T) {
        asm volatile("s_waitcnt vmcnt(0)" ::: "memory");   // tile T landed
        __builtin_amdgcn_sched_barrier(0);
        __builtin_amdgcn_s_barrier();   // all waves: tile T ready; T-1 reads done
        __builtin_amdgcn_sched_barrier(0);
        if (T + 1 < nt) stageT((T + 1) & 1, (T + 1) << 6);

        const char* Abase = (const char*)As[T & 1];
        const char* Bbase = (const char*)Bs[T & 1];
        #pragma unroll
        for (int q = 0; q < 4; ++q) {          // quadrant: (mh, nh)
            const int mh = q >> 1, nh = q & 1;
            bf16x8 af[4][2], bfv[2][2];
            #pragma unroll
            for (int mf = 0; mf < 4; ++mf) {
                const int row = wm * 128 + (mh * 4 + mf) * 16 + l15;
                #pragma unroll
                for (int kk = 0; kk < 2; ++kk)
                    af[mf][kk] = *(const bf16x8*)(Abase + row * 128 +
                                      (((kk * 4 + g) ^ (row & 7)) << 4));
            }
            #pragma unroll
            for (int nf = 0; nf < 2; ++nf) {
                const int row = wn * 64 + (nh * 2 + nf) * 16 + l15;
                #pragma unroll
                for (int kk = 0; kk < 2; ++kk)
                    bfv[nf][kk] = *(const bf16x8*)(Bbase + row * 128 +
                                      (((kk * 4 + g) ^ (row & 7)) << 4));
            }
            __builtin_amdgcn_s_setprio(1);
            #pragma unroll
            for (int kk = 0; kk < 2; ++kk)
                #pragma unroll
                for (int mf = 0; mf < 4; ++mf)
                    #pragma unroll
                    for (int nf = 0; nf < 2; ++nf)
                        acc[mh * 4 + mf][nh * 2 + nf] =
                            __builtin_amdgcn_mfma_f32_16x16x32_bf16(
                                af[mf][kk], bfv[nf][kk],
                                acc[mh * 4 + mf][nh * 2 + nf], 0, 0, 0);
            __builtin_amdgcn_s_setprio(0);
            __builtin_amdgcn_sched_barrier(0);
        }
    }

    const int lr = g * 4;
    const int lc = l15;
    const long cof = h2 * Csh + b2 * Csb;
    #pragma unroll
    for (int mf = 0; mf < 8; ++mf) {
        #pragma unroll
        for (int i = 0; i < 4; ++i) {
            const int r = m0 + wm * 128 + mf * 16 + lr + i;
            #pragma unroll
            for (int nf = 0; nf < 4; ++nf) {
                const int c = n0 + wn * 64 + nf * 16 + lc;
                float v = acc[mf][nf][i];
                if (MODE == M_SUBAUX) {
                    const u16* q = (const u16*)auxp;
                    v = bf2f(q[auxsh * h2 + auxsb * b2 + (long)r * auxld + c]) - v;
                } else if (MODE == M_RELU) {
                    if (bias) v += bias[h2 * biasN + c];
                    v = fmaxf(v, 0.0f);
                } else if (MODE == M_SCALECOL) {
                    const float* cs = (const float*)auxp + auxsh * h2 + auxsb * b2;
                    v *= 1.0f / (1e-9f + cs[c]);
                }
                C[cof + (long)r * ldc + c] = f2bf(v);
            }
        }
    }
}

// MFMA batched GEMM, 128-tile (round-13 structure) — used for K1/K7.
template<int BM, int BN, int MODE, int ZMAP, int SWAPXY>
__global__ __launch_bounds__(256) void mgemm(
    const u16* __restrict__ A, const u16* __restrict__ B, u16* __restrict__ C,
    int Kd, int lda, int ldb, int ldc,
    long Ash, long Asb, long Bsh, long Bsb, long Csh, long Csb, int nB2,
    const float* __restrict__ bias, int biasN,
    const void* __restrict__ auxp, long auxsh, long auxsb, int auxld)
{
    constexpr int WC = (BN == 128) ? 2 : 1;
    constexpr int WR = 4 / WC;
    constexpr int WTM = BM / WR;
    constexpr int WTN = BN / WC;
    constexpr int MF = WTM / 16;
    constexpr int NF = WTN / 16;
    constexpr int NCA = (BM * 64) / 4096;
    constexpr int NCB = (BN * 64) / 4096;
    __shared__ u16 As[2][BM * 32];
    __shared__ u16 Bs[2][BN * 32];

    const int z = blockIdx.z;
    int h2, b2;
    if (ZMAP == 0)      { h2 = z / nB2;      b2 = z % nB2; }
    else if (ZMAP == 1) { h2 = z & 7;        b2 = z >> 3; }
    else                { h2 = (z >> 3) & 7; b2 = ((z >> 6) << 3) | (z & 7); }
    const u16* Ab = A + h2 * Ash + b2 * Asb;
    const u16* Bb = B + h2 * Bsh + b2 * Bsb;
    const int bx = SWAPXY ? blockIdx.y : blockIdx.x;
    const int by = SWAPXY ? blockIdx.x : blockIdx.y;
    const int m0 = bx * BM, n0 = by * BN;
    const int t = threadIdx.x;
    const int lane = t & 63;
    const int w = t >> 6;
    const int wr = w / WC, wc = w % WC;
    const int tb = t * 16;
    const int wb = (t & 192) * 16;

    f32x4 acc[MF][NF];
    #pragma unroll
    for (int m = 0; m < MF; ++m)
        #pragma unroll
        for (int n = 0; n < NF; ++n)
            #pragma unroll
            for (int i = 0; i < 4; ++i) acc[m][n][i] = 0.f;

    const int ko = (lane >> 4) * 16;

    auto stage = [&](int buf, int k0) {
        #pragma unroll
        for (int c = 0; c < NCA; ++c) {
            const int byte = c * 4096 + tb;
            const int row = byte >> 6;
            gload16((const char*)(Ab + (long)(m0 + row) * lda + k0) + (byte & 63),
                    (char*)As[buf] + c * 4096 + wb);
        }
        #pragma unroll
        for (int c = 0; c < NCB; ++c) {
            const int byte = c * 4096 + tb;
            const int row = byte >> 6;
            gload16((const char*)(Bb + (long)(n0 + row) * ldb + k0) + (byte & 63),
                    (char*)Bs[buf] + c * 4096 + wb);
        }
    };

    stage(0, 0);
    __syncthreads();
    int cur = 0;
    const int nsteps = Kd >> 5;
    for (int s = 0; s < nsteps; ++s) {
        if (s + 1 < nsteps) stage(cur ^ 1, (s + 1) << 5);
        bf16x8 af[MF], bfr[NF];
        #pragma unroll
        for (int m = 0; m < MF; ++m)
            af[m] = *(const bf16x8*)((const char*)As[cur] + (wr * WTM + m * 16 + (lane & 15)) * 64 + ko);
        #pragma unroll
        for (int n = 0; n < NF; ++n)
            bfr[n] = *(const bf16x8*)((const char*)Bs[cur] + (wc * WTN + n * 16 + (lane & 15)) * 64 + ko);
        #pragma unroll
        for (int m = 0; m < MF; ++m)
            #pragma unroll
            for (int n = 0; n < NF; ++n)
                acc[m][n] = __builtin_amdgcn_mfma_f32_16x16x32_bf16(af[m], bfr[n], acc[m][n], 0, 0, 0);
        __syncthreads();
        cur ^= 1;
    }

    const int lr = (lane >> 4) * 4;
    const int lc = lane & 15;

    if constexpr (MODE == M_WQK) {
        const int h = (n0 + wc * WTN) >> 6;
        #pragma unroll
        for (int m = 0; m < MF; ++m) {
            #pragma unroll
            for (int i = 0; i < 4; ++i) {
                float s = 0.f;
                #pragma unroll
                for (int n = 0; n < NF; ++n) { const float v = acc[m][n][i]; s += v * v; }
                s += __shfl_xor(s, 1); s += __shfl_xor(s, 2);
                s += __shfl_xor(s, 4); s += __shfl_xor(s, 8);
                const float inv = 1.0f / fmaxf(sqrtf(s), 1e-12f);
                const int r = m0 + wr * WTM + m * 16 + lr + i;  // token = l*B + b
                const int l = r >> 5, bq = r & 31;
                const int sw = (l & 7) << 3;
                u16* rowp = C + (((long)(h * BBATCH + bq) * LLEN + l) * KHEAD);
                #pragma unroll
                for (int n = 0; n < NF; ++n)
                    rowp[(lc + n * 16) ^ sw] = f2bf(acc[m][n][i] * inv);
            }
        }
    } else {
        const long cof = h2 * Csh + b2 * Csb;
        #pragma unroll
        for (int m = 0; m < MF; ++m) {
            #pragma unroll
            for (int i = 0; i < 4; ++i) {
                const int r = m0 + wr * WTM + m * 16 + lr + i;
                #pragma unroll
                for (int n = 0; n < NF; ++n) {
                    const int c = n0 + wc * WTN + n * 16 + lc;
                    float v = acc[m][n][i];
                    if (MODE == M_SUBAUX) {
                        const u16* q = (const u16*)auxp;
                        v = bf2f(q[auxsh * h2 + auxsb * b2 + (long)r * auxld + c]) - v;
                    } else if (MODE == M_RELU) {
                        if (bias) v += bias[h2 * biasN + c];
                        v = fmaxf(v, 0.0f);
                    } else if (MODE == M_ADDAUX) {
                        v += bias[h2 * biasN + c];
                        const u16* ax = (const u16*)auxp;
                        v += bf2f(ax[auxsh * h2 + auxsb * b2 + (long)r * auxld + c]);
                    } else if (MODE == M_SCALECOL) {
                        const float* cs = (const float*)auxp + auxsh * h2 + auxsb * b2;
                        v *= 1.0f / (1e-9f + cs[c]);
                    }
                    C[cof + (long)r * ldc + c] = f2bf(v);
                }
            }
        }
    }
}

// XCD-aware decode: 8 qt-blocks of one (h,b) -> same wgid%8 (same XCD).
__device__ __forceinline__ void xcd_decode(int wgid, int& qt, int& b, int& h) {
    const int r = wgid & 7;
    const int inner = wgid >> 3;
    qt = inner & 7;
    h = (inner >> 3) & 7;
    b = ((inner >> 6) << 3) | r;
}

// MFMA QK^T + softmax -> P (bf16) + column sums (fp32 atomics).
__global__ __launch_bounds__(256) void attn_mfma(
    const u16* __restrict__ wq, const u16* __restrict__ wk,
    u16* __restrict__ P, float* __restrict__ colsum)
{
    __shared__ u16 qs[64 * 64];
    __shared__ u16 ks[512 * 64];
    __shared__ float smax[4][64];
    __shared__ float ssum[4][64];

    int qt, b, h;
    xcd_decode(blockIdx.x, qt, b, h);
    const long hb = h * BBATCH + b;
    const int t = threadIdx.x;
    const int lane = t & 63, w = t >> 6;
    const int wb = (t & 192) * 16;

    const char* qg = (const char*)(wq + (hb * LLEN + qt * 64) * KHEAD);
    const char* kg = (const char*)(wk + hb * LLEN * KHEAD);
    #pragma unroll
    for (int c = 0; c < 2; ++c)
        gload16(qg + c * 4096 + t * 16, (char*)qs + c * 4096 + wb);
    #pragma unroll
    for (int c = 0; c < 16; ++c)
        gload16(kg + c * 4096 + t * 16, (char*)ks + c * 4096 + wb);
    __syncthreads();

    const int l15 = lane & 15;
    const int g = lane >> 4;
    const int swz = (lane & 7) << 4;

    f32x4 acc[4][8];
    #pragma unroll
    for (int m = 0; m < 4; ++m)
        #pragma unroll
        for (int n = 0; n < 8; ++n)
            #pragma unroll
            for (int i = 0; i < 4; ++i) acc[m][n][i] = 0.f;

    #pragma unroll
    for (int kk = 0; kk < 2; ++kk) {
        bf16x8 af[4];
        #pragma unroll
        for (int m = 0; m < 4; ++m) {
            const int row = m * 16 + l15;
            af[m] = *(const bf16x8*)((const char*)qs + row * 128 + ((g * 16 + kk * 64) ^ swz));
        }
        #pragma unroll
        for (int n = 0; n < 8; ++n) {
            const int row = (w * 8 + n) * 16 + l15;
            const bf16x8 bfr = *(const bf16x8*)((const char*)ks + row * 128 + ((g * 16 + kk * 64) ^ swz));
            #pragma unroll
            for (int m = 0; m < 4; ++m)
                acc[m][n] = __builtin_amdgcn_mfma_f32_16x16x32_bf16(af[m], bfr, acc[m][n], 0, 0, 0);
        }
    }

    float rmax[4][4];
    #pragma unroll
    for (int m = 0; m < 4; ++m)
        #pragma unroll
        for (int i = 0; i < 4; ++i) {
            float mx = acc[m][0][i];
            #pragma unroll
            for (int n = 1; n < 8; ++n) mx = fmaxf(mx, acc[m][n][i]);
            mx = fmaxf(mx, __shfl_xor(mx, 1));
            mx = fmaxf(mx, __shfl_xor(mx, 2));
            mx = fmaxf(mx, __shfl_xor(mx, 4));
            mx = fmaxf(mx, __shfl_xor(mx, 8));
            if (l15 == 0) smax[w][m * 16 + g * 4 + i] = mx;
        }
    __syncthreads();
    #pragma unroll
    for (int m = 0; m < 4; ++m)
        #pragma unroll
        for (int i = 0; i < 4; ++i) {
            const int r = m * 16 + g * 4 + i;
            rmax[m][i] = fmaxf(fmaxf(smax[0][r], smax[1][r]),
                               fmaxf(smax[2][r], smax[3][r]));
        }
    float rinv[4][4];
    #pragma unroll
    for (int m = 0; m < 4; ++m)
        #pragma unroll
        for (int i = 0; i < 4; ++i) {
            float s = 0.f;
            #pragma unroll
            for (int n = 0; n < 8; ++n) {
                acc[m][n][i] = __expf(acc[m][n][i] - rmax[m][i]);
                s += acc[m][n][i];
            }
            s += __shfl_xor(s, 1); s += __shfl_xor(s, 2);
            s += __shfl_xor(s, 4); s += __shfl_xor(s, 8);
            if (l15 == 0) ssum[w][m * 16 + g * 4 + i] = s;
        }
    __syncthreads();
    #pragma unroll
    for (int m = 0; m < 4; ++m)
        #pragma unroll
        for (int i = 0; i < 4; ++i) {
            const int r = m * 16 + g * 4 + i;
            rinv[m][i] = 1.0f / (ssum[0][r] + ssum[1][r] + ssum[2][r] + ssum[3][r]);
        }

    u16* Pb = P + (hb * LLEN + qt * 64) * LLEN + w * 128;
    float cs[8];
    #pragma unroll
    for (int n = 0; n < 8; ++n) cs[n] = 0.f;
    #pragma unroll
    for (int m = 0; m < 4; ++m)
        #pragma unroll
        for (int i = 0; i < 4; ++i) {
            const int r = m * 16 + g * 4 + i;
            u16* pr = Pb + (long)r * LLEN + l15;
            const float iv = rinv[m][i];
            #pragma unroll
            for (int n = 0; n < 8; ++n) {
                const float p = acc[m][n][i] * iv;
                pr[n * 16] = f2bf(p);
                cs[n] += p;
            }
        }
    #pragma unroll
    for (int n = 0; n < 8; ++n) {
        cs[n] += __shfl_xor(cs[n], 16);
        cs[n] += __shfl_xor(cs[n], 32);
    }
    if (lane < 16) {
        float* cb = colsum + hb * 512 + w * 128 + lane;
        #pragma unroll
        for (int n = 0; n < 8; ++n) atomicAdd(&cb[n * 16], cs[n]);
    }
}

// Fused: preLN = o + hff @ W2^T + b2, LayerNorm, transpose-scatter fp32.
__global__ __launch_bounds__(256) void ffn2_ln(
    const u16* __restrict__ hff, const u16* __restrict__ W2bf,
    const float* __restrict__ b2, const u16* __restrict__ o,
    const float* __restrict__ lng, const float* __restrict__ lnb,
    float* __restrict__ out)
{
    __shared__ u16 W2s[512 * 64];
    __shared__ u16 hs[32 * 64];
    __shared__ float redS[4][32];
    __shared__ float redQ[4][32];

    const int h = blockIdx.z;
    const int m0 = blockIdx.x * 32;
    const int t = threadIdx.x;
    const int lane = t & 63, w = t >> 6;
    const int l15 = lane & 15, g = lane >> 4;
    const int wb = (t & 192) * 16;

    const char* w2g = (const char*)W2bf + (long)h * 65536;
    #pragma unroll
    for (int c = 0; c < 16; ++c) {
        const int idx = c * 4096 + t * 16;
        const int row = idx >> 7;
        const int g0 = (idx >> 4) & 7;
        gload16(w2g + row * 128 + ((g0 ^ (row & 7)) << 4),
                (char*)W2s + c * 4096 + wb);
    }
    {
        const int idx = t * 16;
        const int row = idx >> 7;
        const int g0 = (idx >> 4) & 7;
        gload16((const char*)(hff + ((long)h * NTOK + m0) * FFD) +
                    row * 128 + ((g0 ^ (row & 7)) << 4),
                (char*)hs + wb);
    }
    __syncthreads();

    f32x4 acc[2][8];
    #pragma unroll
    for (int m = 0; m < 2; ++m)
        #pragma unroll
        for (int n = 0; n < 8; ++n)
            #pragma unroll
            for (int i = 0; i < 4; ++i) acc[m][n][i] = 0.f;

    #pragma unroll
    for (int kk = 0; kk < 2; ++kk) {
        bf16x8 af[2];
        #pragma unroll
        for (int m = 0; m < 2; ++m) {
            const int row = m * 16 + l15;
            af[m] = *(const bf16x8*)((const char*)hs + row * 128 +
                                     (((kk * 4 + g) ^ (row & 7)) << 4));
        }
        #pragma unroll
        for (int n = 0; n < 8; ++n) {
            const int e = w * 128 + n * 16 + l15;
            const bf16x8 bfr = *(const bf16x8*)((const char*)W2s + e * 128 +
                                                (((kk * 4 + g) ^ (e & 7)) << 4));
            #pragma unroll
            for (int m = 0; m < 2; ++m)
                acc[m][n] = __builtin_amdgcn_mfma_f32_16x16x32_bf16(af[m], bfr, acc[m][n], 0, 0, 0);
        }
    }

    float b2v[8], gv[8], bv[8];
    #pragma unroll
    for (int n = 0; n < 8; ++n) {
        const int c = w * 128 + n * 16 + l15;
        b2v[n] = b2[h * DDIM + c];
        gv[n] = lng[h * DDIM + c];
        bv[n] = lnb[h * DDIM + c];
    }
    const u16* ob = o + ((long)h * NTOK + m0) * DDIM;
    #pragma unroll
    for (int m = 0; m < 2; ++m)
        #pragma unroll
        for (int i = 0; i < 4; ++i) {
            const int row = m * 16 + g * 4 + i;
            float s = 0.f, q = 0.f;
            #pragma unroll
            for (int n = 0; n < 8; ++n) {
                const int c = w * 128 + n * 16 + l15;
                const float v = acc[m][n][i] + b2v[n] + bf2f(ob[(long)row * DDIM + c]);
                acc[m][n][i] = v;
                s += v; q += v * v;
            }
            s += __shfl_xor(s, 1); q += __shfl_xor(q, 1);
            s += __shfl_xor(s, 2); q += __shfl_xor(q, 2);
            s += __shfl_xor(s, 4); q += __shfl_xor(q, 4);
            s += __shfl_xor(s, 8); q += __shfl_xor(q, 8);
            if (l15 == 0) { redS[w][row] = s; redQ[w][row] = q; }
        }
    __syncthreads();

    #pragma unroll
    for (int m = 0; m < 2; ++m)
        #pragma unroll
        for (int i = 0; i < 4; ++i) {
            const int row = m * 16 + g * 4 + i;
            const float s = redS[0][row] + redS[1][row] + redS[2][row] + redS[3][row];
            const float q = redQ[0][row] + redQ[1][row] + redQ[2][row] + redQ[3][row];
            const float mu = s * (1.0f / 512.0f);
            const float var = q * (1.0f / 512.0f) - mu * mu;
            const float rs = rsqrtf(var + 1e-5f);
            const int tok = m0 + row;
            const int b = tok >> 9, l = tok & 511;   // tok = b*512 + l
            float* op = out + ((long)(l * BBATCH + b)) * (HH * DDIM) + h * DDIM;
            #pragma unroll
            for (int n = 0; n < 8; ++n) {
                const int c = w * 128 + n * 16 + l15;
                op[c] = (acc[m][n][i] - mu) * rs * gv[n] + bv[n];
            }
        }
}

extern "C" void kernel_launch(void* const* d_in, const int* in_sizes, int n_in,
                              void* d_out, int out_size, void* d_ws, size_t ws_size,
                              hipStream_t stream) {
    const float* query = (const float*)d_in[0];
    const float* key   = (const float*)d_in[1];
    const float* value = (const float*)d_in[2];
    const float* WK = (const float*)d_in[3];
    const float* WQ = (const float*)d_in[4];
    const float* WV = (const float*)d_in[5];
    const float* Wt = (const float*)d_in[6];
    const float* W1 = (const float*)d_in[7];
    const float* b1 = (const float*)d_in[8];
    const float* W2 = (const float*)d_in[9];
    const float* b2 = (const float*)d_in[10];
    const float* lng = (const float*)d_in[11];
    const float* lnb = (const float*)d_in[12];

    // ---- workspace layout (bytes), peak 319,291,392 ----
    char* ws = (char*)d_ws;
    u16* kbf  = (u16*)(ws);                    // 16 MB
    u16* WQbf = (u16*)(ws + 16777216);         // 0.5 MB
    u16* WKbf = (u16*)(ws + 17301504);         // 0.5 MB
    u16* P    = (u16*)(ws);                    // 128 MB
    u16* vbf  = (u16*)(ws + 134217728);        // 16 MB
    u16* WVbf = (u16*)(ws + 150994944);        // 0.5 MB
    u16* o    = (u16*)(ws + 134217728);        // 128 MB (from K6)
    float* colsum = (float*)(ws + 268435456);  // 0.5 MB
    u16* qbf  = (u16*)(ws + 268959744);        // 16 MB, dead after K5
    u16* hff  = qbf;                           // overlay, produced at K7
    u16* wq   = (u16*)(ws + 285736960);        // 16 MB
    u16* wk   = (u16*)(ws + 302514176);        // 16 MB
    u16* Wtbf = (u16*)(ws + 285736960);        // 4 MB (into dead wq)
    u16* W1bf = (u16*)(ws + 289931264);        // 0.5 MB
    u16* W2bf = (u16*)(ws + 290455552);        // 0.5 MB
    u16* qmo = (u16*)d_out;                        // [H][B][L][D]
    u16* wvT = (u16*)((char*)d_out + 134217728);   // [H][B][D][L]

    if (ws_size < 319291392u) return;

    hipMemsetAsync(colsum, 0, 524288, stream);
    const dim3 blk(256);

    // conv batch 1: inputs + QKV projection weights
    {
        ConvJobs J;
        J.j[0] = { query, qbf, 2097152 };
        J.j[1] = { key,   kbf, 2097152 };
        J.j[2] = { value, vbf, 2097152 };
        J.j[3] = { WQ, WQbf, 65536 };
        J.j[4] = { WK, WKbf, 65536 };
        J.j[5] = { WV, WVbf, 524288 };
        J.nj = 6;
        conv_multi<<<dim3(2048), blk, 0, stream>>>(J);
    }

    // K1: wq/wk = l2norm(query/key @ WQ/WK^T) -> [H,B,L,K] bf16 (swizzled rows)
    mgemm<128, 128, M_WQK, 0, 1><<<dim3(4, 128, 1), blk, 0, stream>>>(
        qbf, WQbf, wq, 512, 512, 512, 0,
        0, 0, 0, 0, 0, 0, 1, nullptr, 0, nullptr, 0, 0, 0);
    mgemm<128, 128, M_WQK, 0, 1><<<dim3(4, 128, 1), blk, 0, stream>>>(
        kbf, WKbf, wk, 512, 512, 512, 0,
        0, 0, 0, 0, 0, 0, 1, nullptr, 0, nullptr, 0, 0, 0);

    // attn: softmax(QK^T) -> P + colsum, XCD-aware grid
    attn_mfma<<<dim3(2048), blk, 0, stream>>>(wq, wk, P, colsum);

    // conv batch 2: FFN weights into the now-dead wq region
    {
        ConvJobs J;
        J.j[0] = { Wt, Wtbf, 524288 };
        J.j[1] = { W1, W1bf, 65536 };
        J.j[2] = { W2, W2bf, 65536 };
        J.nj = 3;
        conv_multi<<<dim3(1024), blk, 0, stream>>>(J);
    }

    // K2: wvT[h,b,e,l] = (WV @ value^T) / (1e-9 + colsum[h,b,l])  [256² tile]
    mgemm256<M_SCALECOL, 2, 0><<<dim3(2, 2, 256), dim3(512), 0, stream>>>(
        WVbf, vbf, wvT, 512, 512, BBATCH * DDIM, 512,
        (long)DDIM * DDIM, 0, 0, DDIM,
        (long)BBATCH * DDIM * LLEN, (long)DDIM * LLEN, 32,
        nullptr, 0, colsum, (long)BBATCH * 512, 512, 0);

    // K5: qmo = query - P @ wvT^T   [256² tile, b-major z]
    mgemm256<M_SUBAUX, 1, 0><<<dim3(2, 2, 256), dim3(512), 0, stream>>>(
        P, wvT, qmo, 512, 512, 512, 512,
        (long)BBATCH * LLEN * LLEN, (long)LLEN * LLEN,
        (long)BBATCH * DDIM * LLEN, (long)DDIM * LLEN,
        (long)BBATCH * LLEN * DDIM, (long)LLEN * DDIM, 32,
        nullptr, 0, qbf, 0, DDIM, BBATCH * DDIM);

    // K6: o = relu(qmo @ Wt^T)   [256² tile, SWAPXY]
    mgemm256<M_RELU, 0, 1><<<dim3(2, 64, 8), dim3(512), 0, stream>>>(
        qmo, Wtbf, o, 512, 512, 512, 512,
        (long)NTOK * DDIM, 0, (long)DDIM * DDIM, 0,
        (long)NTOK * DDIM, 0, 1, nullptr, 512, nullptr, 0, 0, 0);

    // K7: hff = relu(o @ W1^T + b1)   (BN=64)
    mgemm<128, 64, M_RELU, 0, 0><<<dim3(128, 1, 8), blk, 0, stream>>>(
        o, W1bf, hff, 512, 512, 512, 64,
        (long)NTOK * DDIM, 0, (long)FFD * DDIM, 0,
        (long)NTOK * FFD, 0, 1, b1, 64, nullptr, 0, 0, 0);

    // K8 + LN + transpose fused
    ffn2_ln<<<dim3(512, 1, 8), blk, 0, stream>>>(hff, W2bf, b2, o, lng, lnb,
                                                 (float*)d_out);
}